// Round 1
// baseline (813.608 us; speedup 1.0000x reference)
//
#include <hip/hip_runtime.h>
#include <hip/hip_bf16.h>

#define NTOK 577
#define CH 768
#define NH 12
#define HD 64
#define M_ROWS 9232      // B * N
#define MPV 640          // m pitch of vT (5 * 128)
#define LDP 40           // padded LDS row pitch (f16) for GEMM tiles

typedef _Float16 f16x8 __attribute__((ext_vector_type(8)));
typedef _Float16 f16x4 __attribute__((ext_vector_type(4)));
typedef float f32x4 __attribute__((ext_vector_type(4)));

#define MFMA16(a, b, c) __builtin_amdgcn_mfma_f32_16x16x32_f16((a), (b), (c), 0, 0, 0)

__device__ __forceinline__ float bf2f(unsigned int u16) {
  union { unsigned int i; float f; } x; x.i = u16 << 16; return x.f;
}

__device__ __forceinline__ float ldin(const void* p, size_t i, bool f32) {
  return f32 ? ((const float*)p)[i]
             : __bfloat162float(((const __hip_bfloat16*)p)[i]);
}

__device__ __forceinline__ f16x8 ld8_cvt(const void* p, size_t idx, bool f32) {
  f16x8 r;
  if (f32) {
    const float* f = (const float*)p + idx;
    const float4 u = *(const float4*)f;
    const float4 v = *(const float4*)(f + 4);
    r[0]=(_Float16)u.x; r[1]=(_Float16)u.y; r[2]=(_Float16)u.z; r[3]=(_Float16)u.w;
    r[4]=(_Float16)v.x; r[5]=(_Float16)v.y; r[6]=(_Float16)v.z; r[7]=(_Float16)v.w;
  } else {
    const unsigned short* s = (const unsigned short*)p + idx;
    uint4 u = *(const uint4*)s;
    unsigned int w0=u.x, w1=u.y, w2=u.z, w3=u.w;
    r[0]=(_Float16)bf2f(w0&0xffffu); r[1]=(_Float16)bf2f(w0>>16);
    r[2]=(_Float16)bf2f(w1&0xffffu); r[3]=(_Float16)bf2f(w1>>16);
    r[4]=(_Float16)bf2f(w2&0xffffu); r[5]=(_Float16)bf2f(w2>>16);
    r[6]=(_Float16)bf2f(w3&0xffffu); r[7]=(_Float16)bf2f(w3>>16);
  }
  return r;
}

// ---- Kernel 0: detect input dtype (fp32 vs bf16).
__global__ void detect_dtype(const unsigned short* __restrict__ xs,
                             int* __restrict__ flag) {
  __shared__ int cnt;
  if (threadIdx.x == 0) cnt = 0;
  __syncthreads();
  int local = 0;
  for (int i = threadIdx.x; i < 4096; i += 256) {
    unsigned int u = xs[2 * i];
    unsigned int e = (u >> 7) & 0xFFu;
    if (e >= 140u) local++;
  }
  atomicAdd(&cnt, local);
  __syncthreads();
  if (threadIdx.x == 0) *flag = (cnt > 100) ? 1 : 0;
}

// ---- Kernel 1: qkv = x @ Wqkv^T via MFMA 16x16x32 f16, 128x128 tiles.
__global__ __launch_bounds__(256) void gemm_qkv_mfma(
    const void* __restrict__ X, const void* __restrict__ W,
    const int* __restrict__ flagp,
    _Float16* __restrict__ q, _Float16* __restrict__ k,
    _Float16* __restrict__ vT)
{
  const bool f32 = (*flagp != 0);
  __shared__ _Float16 As[128 * LDP];
  __shared__ _Float16 Bs[128 * LDP];
  const int tid = threadIdx.x;
  const int lane = tid & 63, wave = tid >> 6;
  const int quad = lane >> 4, l16 = lane & 15;
  const int wm = wave & 1, wo = wave >> 1;
  const int m0 = blockIdx.y * 128;
  const int bx = blockIdx.x;
  const int t = bx / 6;                    // 0=q 1=k 2=v
  const int o0 = bx * 128;
  const int o0loc = o0 - t * CH;

  const int srow = tid >> 2;
  const int scol = (tid & 3) * 8;
  const int arow0 = min(m0 + srow, M_ROWS - 1);
  const int arow1 = min(m0 + srow + 64, M_ROWS - 1);
  const int brow0 = o0 + srow;
  const int brow1 = o0 + srow + 64;

  f16x8 ra[2], rb[2];
  ra[0] = ld8_cvt(X, (size_t)arow0 * CH + scol, f32);
  ra[1] = ld8_cvt(X, (size_t)arow1 * CH + scol, f32);
  rb[0] = ld8_cvt(W, (size_t)brow0 * CH + scol, f32);
  rb[1] = ld8_cvt(W, (size_t)brow1 * CH + scol, f32);

  f32x4 acc[4][4] = {};
  for (int ks = 0; ks < CH / 32; ++ks) {
    __syncthreads();
    *(f16x8*)&As[(srow)      * LDP + scol] = ra[0];
    *(f16x8*)&As[(srow + 64) * LDP + scol] = ra[1];
    *(f16x8*)&Bs[(srow)      * LDP + scol] = rb[0];
    *(f16x8*)&Bs[(srow + 64) * LDP + scol] = rb[1];
    __syncthreads();
    if (ks + 1 < CH / 32) {
      int kc = (ks + 1) * 32 + scol;
      ra[0] = ld8_cvt(X, (size_t)arow0 * CH + kc, f32);
      ra[1] = ld8_cvt(X, (size_t)arow1 * CH + kc, f32);
      rb[0] = ld8_cvt(W, (size_t)brow0 * CH + kc, f32);
      rb[1] = ld8_cvt(W, (size_t)brow1 * CH + kc, f32);
    }
    f16x8 af[4], bf_[4];
    #pragma unroll
    for (int i = 0; i < 4; ++i)
      af[i] = *(const f16x8*)&As[(wm * 64 + i * 16 + l16) * LDP + quad * 8];
    #pragma unroll
    for (int j = 0; j < 4; ++j)
      bf_[j] = *(const f16x8*)&Bs[(wo * 64 + j * 16 + l16) * LDP + quad * 8];
    #pragma unroll
    for (int i = 0; i < 4; ++i)
      #pragma unroll
      for (int j = 0; j < 4; ++j)
        acc[i][j] = MFMA16(af[i], bf_[j], acc[i][j]);
  }

  #pragma unroll
  for (int i = 0; i < 4; ++i) {
    #pragma unroll
    for (int rr = 0; rr < 4; ++rr) {
      int m = m0 + wm * 64 + i * 16 + quad * 4 + rr;
      if (m >= M_ROWS) continue;
      int b = m / NTOK, n = m - b * NTOK;
      #pragma unroll
      for (int j = 0; j < 4; ++j) {
        int o = o0loc + wo * 64 + j * 16 + l16;
        int h = o >> 6, dd = o & 63;
        _Float16 val = (_Float16)acc[i][j][rr];
        if (t == 0)
          q[((size_t)(b * NH + h) * NTOK + n) * HD + dd] = val;
        else if (t == 1)
          k[((size_t)(b * NH + h) * NTOK + n) * HD + dd] = val;
        else
          vT[((size_t)(b * NH + h) * HD + dd) * MPV + n] = val;
      }
    }
  }
}

// ---- zero the m-pad of vT (m in [577,640)).
__global__ void zerofill_vt(_Float16* __restrict__ vT) {
  int idx = blockIdx.x * 256 + threadIdx.x;
  int r = idx >> 6, c = idx & 63;
  if (r < 16 * NH * HD && c < MPV - NTOK)
    vT[(size_t)r * MPV + NTOK + c] = (_Float16)0.f;
}

// ---- Kernel 2 (fused): QK^T + Wpre mix + exp, rowsum pass, then recompute
// + normalize + Wpost mix + PV — no E intermediate in HBM.
// QK is computed SWAPPED (A=K, B=Q) so the C layout is (m = quad*4+r,
// n = l16): rowsum is a lane-local 4-accumulate + quad shfl-reduce, rinv is
// one scalar per (g, lane), and the P2 write is a contiguous f16x4.
// Qs/P2s are XOR-swizzled [x][16][64] f16 tiles: idx ^= (n&7)<<3 spreads the
// 128 B row stride over 8 bank slots (b128 reads at the 8-cycle floor).
__global__ __launch_bounds__(256) void fused_attn(
    const _Float16* __restrict__ q, const _Float16* __restrict__ k,
    const _Float16* __restrict__ vT, const void* __restrict__ Wpre,
    const void* __restrict__ Wpost, const int* __restrict__ flagp,
    _Float16* __restrict__ o1)
{
  const bool f32 = (*flagp != 0);
  __shared__ _Float16 Qs[NH * 16 * 64];    // swizzled [h][n16][d64]
  __shared__ _Float16 P2s[NH * 16 * 64];   // swizzled [g][n16][m64]
  __shared__ float wp[NH * NH];
  __shared__ _Float16 w2h[NH * NH];
  __shared__ float rinvs[NH * 16];
  float* wsumf = (float*)P2s;              // alias: pass-1 reduction scratch

  const int tid = threadIdx.x;
  const int lane = tid & 63, w = tid >> 6;
  const int quad = lane >> 4, l16 = lane & 15;
  const int b = blockIdx.y;
  const int n0 = blockIdx.x * 16;
  const int swq = (l16 & 7) << 3;          // f16-index XOR swizzle for row l16

  if (tid < NH * NH) {
    wp[tid]  = ldin(Wpre, tid, f32) * 0.125f;   // fold d^-0.5
    w2h[tid] = (_Float16)ldin(Wpost, tid, f32);
  }
  // stage Q tile: 12h x 16n x 64d = 1536 f16x8 loads, 6 per thread
  #pragma unroll
  for (int it = 0; it < 6; ++it) {
    int idx = it * 256 + tid;
    int row = idx >> 3, cseg = (idx & 7) * 8;
    int h = row >> 4, n = row & 15;
    int gn = min(n0 + n, NTOK - 1);
    f16x8 v = *(const f16x8*)(q + ((size_t)(b * NH + h) * NTOK + gn) * HD + cseg);
    *(f16x8*)&Qs[h * 1024 + n * 64 + (cseg ^ ((n & 7) << 3))] = v;
  }
  __syncthreads();

  // ---- pass 1: rowsum[g][n] = sum_m exp(mix_pre(QK^T))
  float rs[NH];
  #pragma unroll
  for (int g = 0; g < NH; ++g) rs[g] = 0.f;

  for (int c = 0; c < 10; ++c) {
    const int bm0 = c * 64 + w * 16;
    const int mk = min(bm0 + l16, NTOK - 1);
    f32x4 acc[NH];
    #pragma unroll
    for (int h = 0; h < NH; ++h) {
      const _Float16* kp = k + ((size_t)(b * NH + h) * NTOK + mk) * HD + quad * 8;
      f16x8 a0 = *(const f16x8*)kp;
      f16x8 a1 = *(const f16x8*)(kp + 32);
      f16x8 q0 = *(const f16x8*)&Qs[h * 1024 + l16 * 64 + ((quad * 8) ^ swq)];
      f16x8 q1 = *(const f16x8*)&Qs[h * 1024 + l16 * 64 + ((quad * 8 + 32) ^ swq)];
      f32x4 z = {0.f, 0.f, 0.f, 0.f};
      z = MFMA16(a0, q0, z);
      acc[h] = MFMA16(a1, q1, z);
    }
    const int mo = bm0 + quad * 4;
    const bool v0 = mo + 0 < NTOK, v1 = mo + 1 < NTOK;
    const bool v2 = mo + 2 < NTOK, v3 = mo + 3 < NTOK;
    #pragma unroll
    for (int g = 0; g < NH; ++g) {
      float s0 = 0.f, s1 = 0.f, s2 = 0.f, s3 = 0.f;
      #pragma unroll
      for (int h = 0; h < NH; ++h) {
        const float ww = wp[g * NH + h];
        s0 += ww * acc[h][0]; s1 += ww * acc[h][1];
        s2 += ww * acc[h][2]; s3 += ww * acc[h][3];
      }
      float e0 = v0 ? __expf(s0) : 0.f;
      float e1 = v1 ? __expf(s1) : 0.f;
      float e2 = v2 ? __expf(s2) : 0.f;
      float e3 = v3 ? __expf(s3) : 0.f;
      rs[g] += (e0 + e1) + (e2 + e3);
    }
  }
  // reduce over quads (shfl) then waves (LDS, aliased into P2s)
  #pragma unroll
  for (int g = 0; g < NH; ++g) {
    rs[g] += __shfl_xor(rs[g], 16);
    rs[g] += __shfl_xor(rs[g], 32);
  }
  if (quad == 0) {
    #pragma unroll
    for (int g = 0; g < NH; ++g)
      wsumf[(w * NH + g) * 16 + l16] = rs[g];
  }
  __syncthreads();
  if (tid < NH * 16) {
    int g = tid >> 4, n = tid & 15;
    float tot = wsumf[(0 * NH + g) * 16 + n] + wsumf[(1 * NH + g) * 16 + n]
              + wsumf[(2 * NH + g) * 16 + n] + wsumf[(3 * NH + g) * 16 + n];
    rinvs[g * 16 + n] = tot > 0.f ? 1.f / tot : 0.f;
  }
  __syncthreads();
  float rinv[NH];
  #pragma unroll
  for (int g = 0; g < NH; ++g) rinv[g] = rinvs[g * 16 + l16];

  // ---- pass 2: recompute QK, normalize + Wpost mix -> P2s, PV via MFMA
  f32x4 O[3][4];
  #pragma unroll
  for (int j = 0; j < 3; ++j)
    #pragma unroll
    for (int dt = 0; dt < 4; ++dt) O[j][dt] = (f32x4){0.f, 0.f, 0.f, 0.f};
  const int gg0 = w * 3;

  for (int c = 0; c < 10; ++c) {
    const int bm0 = c * 64 + w * 16;
    const int mk = min(bm0 + l16, NTOK - 1);
    f32x4 acc[NH];
    #pragma unroll
    for (int h = 0; h < NH; ++h) {
      const _Float16* kp = k + ((size_t)(b * NH + h) * NTOK + mk) * HD + quad * 8;
      f16x8 a0 = *(const f16x8*)kp;
      f16x8 a1 = *(const f16x8*)(kp + 32);
      f16x8 q0 = *(const f16x8*)&Qs[h * 1024 + l16 * 64 + ((quad * 8) ^ swq)];
      f16x8 q1 = *(const f16x8*)&Qs[h * 1024 + l16 * 64 + ((quad * 8 + 32) ^ swq)];
      f32x4 z = {0.f, 0.f, 0.f, 0.f};
      z = MFMA16(a0, q0, z);
      acc[h] = MFMA16(a1, q1, z);
    }
    const int mo = bm0 + quad * 4;
    const bool v0 = mo + 0 < NTOK, v1 = mo + 1 < NTOK;
    const bool v2 = mo + 2 < NTOK, v3 = mo + 3 < NTOK;
    f16x4 en[NH];
    #pragma unroll
    for (int g = 0; g < NH; ++g) {
      float s0 = 0.f, s1 = 0.f, s2 = 0.f, s3 = 0.f;
      #pragma unroll
      for (int h = 0; h < NH; ++h) {
        const float ww = wp[g * NH + h];
        s0 += ww * acc[h][0]; s1 += ww * acc[h][1];
        s2 += ww * acc[h][2]; s3 += ww * acc[h][3];
      }
      float e0 = v0 ? __expf(s0) : 0.f;
      float e1 = v1 ? __expf(s1) : 0.f;
      float e2 = v2 ? __expf(s2) : 0.f;
      float e3 = v3 ? __expf(s3) : 0.f;
      const float rg = rinv[g];
      f16x4 t;
      t[0] = (_Float16)(e0 * rg); t[1] = (_Float16)(e1 * rg);
      t[2] = (_Float16)(e2 * rg); t[3] = (_Float16)(e3 * rg);
      en[g] = t;
    }
    __syncthreads();   // previous chunk's P2s readers done
    #pragma unroll
    for (int gp = 0; gp < NH; ++gp) {
      f16x4 p = en[0] * w2h[gp * NH + 0];
      #pragma unroll
      for (int h = 1; h < NH; ++h) p += en[h] * w2h[gp * NH + h];
      *(f16x4*)&P2s[gp * 1024 + l16 * 64 + ((w * 16 + quad * 4) ^ swq)] = p;
    }
    __syncthreads();
    #pragma unroll
    for (int kc = 0; kc < 2; ++kc) {
      #pragma unroll
      for (int j = 0; j < 3; ++j) {
        const int g = gg0 + j;
        f16x8 a = *(const f16x8*)&P2s[g * 1024 + l16 * 64 + ((kc * 32 + quad * 8) ^ swq)];
        #pragma unroll
        for (int dt = 0; dt < 4; ++dt) {
          f16x8 bv = *(const f16x8*)(
              vT + ((size_t)(b * NH + g) * HD + dt * 16 + l16) * MPV
                 + c * 64 + kc * 32 + quad * 8);
          O[j][dt] = MFMA16(a, bv, O[j][dt]);
        }
      }
    }
  }
  #pragma unroll
  for (int j = 0; j < 3; ++j)
    #pragma unroll
    for (int dt = 0; dt < 4; ++dt)
      #pragma unroll
      for (int r = 0; r < 4; ++r) {
        int n = n0 + quad * 4 + r;
        if (n < NTOK)
          o1[((size_t)b * NTOK + n) * CH + (gg0 + j) * HD + dt * 16 + l16] =
              (_Float16)O[j][dt][r];
      }
}

// ---- Kernel 4: out = o1 @ Wproj^T + bproj via MFMA, 128x128 tiles.
__global__ __launch_bounds__(256) void gemm_proj_mfma(
    const _Float16* __restrict__ A, const void* __restrict__ W,
    const void* __restrict__ bias, const int* __restrict__ flagp,
    void* __restrict__ out)
{
  const bool f32 = (*flagp != 0);
  __shared__ _Float16 As[128 * LDP];
  __shared__ _Float16 Bs[128 * LDP];
  const int tid = threadIdx.x;
  const int lane = tid & 63, wave = tid >> 6;
  const int quad = lane >> 4, l16 = lane & 15;
  const int wm = wave & 1, wo = wave >> 1;
  const int m0 = blockIdx.y * 128;
  const int o0 = blockIdx.x * 128;

  const int srow = tid >> 2;
  const int scol = (tid & 3) * 8;
  const int arow0 = min(m0 + srow, M_ROWS - 1);
  const int arow1 = min(m0 + srow + 64, M_ROWS - 1);
  const int brow0 = o0 + srow;
  const int brow1 = o0 + srow + 64;

  f16x8 ra[2], rb[2];
  ra[0] = *(const f16x8*)(A + (size_t)arow0 * CH + scol);
  ra[1] = *(const f16x8*)(A + (size_t)arow1 * CH + scol);
  rb[0] = ld8_cvt(W, (size_t)brow0 * CH + scol, f32);
  rb[1] = ld8_cvt(W, (size_t)brow1 * CH + scol, f32);

  f32x4 acc[4][4] = {};
  for (int ks = 0; ks < CH / 32; ++ks) {
    __syncthreads();
    *(f16x8*)&As[(srow)      * LDP + scol] = ra[0];
    *(f16x8*)&As[(srow + 64) * LDP + scol] = ra[1];
    *(f16x8*)&Bs[(srow)      * LDP + scol] = rb[0];
    *(f16x8*)&Bs[(srow + 64) * LDP + scol] = rb[1];
    __syncthreads();
    if (ks + 1 < CH / 32) {
      int kc = (ks + 1) * 32 + scol;
      ra[0] = *(const f16x8*)(A + (size_t)arow0 * CH + kc);
      ra[1] = *(const f16x8*)(A + (size_t)arow1 * CH + kc);
      rb[0] = ld8_cvt(W, (size_t)brow0 * CH + kc, f32);
      rb[1] = ld8_cvt(W, (size_t)brow1 * CH + kc, f32);
    }
    f16x8 af[4], bf_[4];
    #pragma unroll
    for (int i = 0; i < 4; ++i)
      af[i] = *(const f16x8*)&As[(wm * 64 + i * 16 + l16) * LDP + quad * 8];
    #pragma unroll
    for (int j = 0; j < 4; ++j)
      bf_[j] = *(const f16x8*)&Bs[(wo * 64 + j * 16 + l16) * LDP + quad * 8];
    #pragma unroll
    for (int i = 0; i < 4; ++i)
      #pragma unroll
      for (int j = 0; j < 4; ++j)
        acc[i][j] = MFMA16(af[i], bf_[j], acc[i][j]);
  }

  #pragma unroll
  for (int i = 0; i < 4; ++i) {
    #pragma unroll
    for (int rr = 0; rr < 4; ++rr) {
      int m = m0 + wm * 64 + i * 16 + quad * 4 + rr;
      if (m >= M_ROWS) continue;
      #pragma unroll
      for (int j = 0; j < 4; ++j) {
        int o = o0 + wo * 64 + j * 16 + l16;
        float val = acc[i][j][rr] + ldin(bias, o, f32);
        if (f32) ((float*)out)[(size_t)m * CH + o] = val;
        else ((__hip_bfloat16*)out)[(size_t)m * CH + o] = __float2bfloat16(val);
      }
    }
  }
}

extern "C" void kernel_launch(void* const* d_in, const int* in_sizes, int n_in,
                              void* d_out, int out_size, void* d_ws, size_t ws_size,
                              hipStream_t stream) {
  const void* x     = d_in[0];
  const void* Wqkv  = d_in[1];
  const void* Wproj = d_in[2];
  const void* bproj = d_in[3];
  const void* Wpre  = d_in[4];
  const void* Wpost = d_in[5];

  int* flag = (int*)d_ws;
  _Float16* ws = (_Float16*)((char*)d_ws + 16);
  const size_t QE  = (size_t)16 * NH * NTOK * HD;   // 7,090,176
  const size_t VTE = (size_t)16 * NH * HD * MPV;    // 7,864,320
  _Float16* q   = ws;
  _Float16* k   = q + QE;
  _Float16* vT  = k + QE;
  _Float16* o1  = vT + VTE;

  dim3 blk(256);
  hipLaunchKernelGGL(detect_dtype, dim3(1), blk, 0, stream,
                     (const unsigned short*)x, flag);
  hipLaunchKernelGGL(gemm_qkv_mfma, dim3(18, 73), blk, 0, stream,
                     x, Wqkv, flag, q, k, vT);
  hipLaunchKernelGGL(zerofill_vt, dim3(16 * NH * HD * 64 / 256), blk, 0, stream, vT);
  hipLaunchKernelGGL(fused_attn, dim3(37, 16), blk, 0, stream,
                     q, k, vT, Wpre, Wpost, flag, o1);
  hipLaunchKernelGGL(gemm_proj_mfma, dim3(6, 73), blk, 0, stream,
                     o1, Wproj, bproj, flag, d_out);
}

// Round 2
// 584.573 us; speedup vs baseline: 1.3918x; 1.3918x over previous
//
#include <hip/hip_runtime.h>
#include <hip/hip_bf16.h>

#define NTOK 577
#define CH 768
#define NH 12
#define HD 64
#define M_ROWS 9232      // B * N
#define NPAD 592         // n pitch of E
#define MPV 640          // m pitch of vT and E (5 * 128)
#define LDP 40           // padded LDS row pitch (f16) for GEMM tiles
#define ESP 72           // qk_exp LDS E-tile pitch (f16): 144 B = 9*16 aligned

typedef _Float16 f16x8 __attribute__((ext_vector_type(8)));
typedef float f32x4 __attribute__((ext_vector_type(4)));

#define MFMA16(a, b, c) __builtin_amdgcn_mfma_f32_16x16x32_f16((a), (b), (c), 0, 0, 0)

// barrier that does NOT drain vmcnt: LDS deps need lgkmcnt(0) only, so our
// in-flight global prefetch survives the barrier (HIP's __syncthreads emits
// s_waitcnt vmcnt(0) which would serialize the E-prefetch pipeline).
#define BAR() asm volatile("s_waitcnt lgkmcnt(0)\n\ts_barrier" ::: "memory")

__device__ __forceinline__ float bf2f(unsigned int u16) {
  union { unsigned int i; float f; } x; x.i = u16 << 16; return x.f;
}

__device__ __forceinline__ float ldin(const void* p, size_t i, bool f32) {
  return f32 ? ((const float*)p)[i]
             : __bfloat162float(((const __hip_bfloat16*)p)[i]);
}

__device__ __forceinline__ f16x8 ld8_cvt(const void* p, size_t idx, bool f32) {
  f16x8 r;
  if (f32) {
    const float* f = (const float*)p + idx;
    const float4 u = *(const float4*)f;
    const float4 v = *(const float4*)(f + 4);
    r[0]=(_Float16)u.x; r[1]=(_Float16)u.y; r[2]=(_Float16)u.z; r[3]=(_Float16)u.w;
    r[4]=(_Float16)v.x; r[5]=(_Float16)v.y; r[6]=(_Float16)v.z; r[7]=(_Float16)v.w;
  } else {
    const unsigned short* s = (const unsigned short*)p + idx;
    uint4 u = *(const uint4*)s;
    unsigned int w0=u.x, w1=u.y, w2=u.z, w3=u.w;
    r[0]=(_Float16)bf2f(w0&0xffffu); r[1]=(_Float16)bf2f(w0>>16);
    r[2]=(_Float16)bf2f(w1&0xffffu); r[3]=(_Float16)bf2f(w1>>16);
    r[4]=(_Float16)bf2f(w2&0xffffu); r[5]=(_Float16)bf2f(w2>>16);
    r[6]=(_Float16)bf2f(w3&0xffffu); r[7]=(_Float16)bf2f(w3>>16);
  }
  return r;
}

// ---- Kernel 0: detect input dtype (fp32 vs bf16).
__global__ void detect_dtype(const unsigned short* __restrict__ xs,
                             int* __restrict__ flag) {
  __shared__ int cnt;
  if (threadIdx.x == 0) cnt = 0;
  __syncthreads();
  int local = 0;
  for (int i = threadIdx.x; i < 4096; i += 256) {
    unsigned int u = xs[2 * i];
    unsigned int e = (u >> 7) & 0xFFu;
    if (e >= 140u) local++;
  }
  atomicAdd(&cnt, local);
  __syncthreads();
  if (threadIdx.x == 0) *flag = (cnt > 100) ? 1 : 0;
}

// ---- Kernel 1: qkv = x @ Wqkv^T via MFMA 16x16x32 f16, 128x128 tiles.
__global__ __launch_bounds__(256) void gemm_qkv_mfma(
    const void* __restrict__ X, const void* __restrict__ W,
    const int* __restrict__ flagp,
    _Float16* __restrict__ q, _Float16* __restrict__ k,
    _Float16* __restrict__ vT)
{
  const bool f32 = (*flagp != 0);
  __shared__ _Float16 As[128 * LDP];
  __shared__ _Float16 Bs[128 * LDP];
  const int tid = threadIdx.x;
  const int lane = tid & 63, wave = tid >> 6;
  const int quad = lane >> 4, l16 = lane & 15;
  const int wm = wave & 1, wo = wave >> 1;
  const int m0 = blockIdx.y * 128;
  const int bx = blockIdx.x;
  const int t = bx / 6;                    // 0=q 1=k 2=v
  const int o0 = bx * 128;
  const int o0loc = o0 - t * CH;

  const int srow = tid >> 2;
  const int scol = (tid & 3) * 8;
  const int arow0 = min(m0 + srow, M_ROWS - 1);
  const int arow1 = min(m0 + srow + 64, M_ROWS - 1);
  const int brow0 = o0 + srow;
  const int brow1 = o0 + srow + 64;

  f16x8 ra[2], rb[2];
  ra[0] = ld8_cvt(X, (size_t)arow0 * CH + scol, f32);
  ra[1] = ld8_cvt(X, (size_t)arow1 * CH + scol, f32);
  rb[0] = ld8_cvt(W, (size_t)brow0 * CH + scol, f32);
  rb[1] = ld8_cvt(W, (size_t)brow1 * CH + scol, f32);

  f32x4 acc[4][4] = {};
  for (int ks = 0; ks < CH / 32; ++ks) {
    __syncthreads();
    *(f16x8*)&As[(srow)      * LDP + scol] = ra[0];
    *(f16x8*)&As[(srow + 64) * LDP + scol] = ra[1];
    *(f16x8*)&Bs[(srow)      * LDP + scol] = rb[0];
    *(f16x8*)&Bs[(srow + 64) * LDP + scol] = rb[1];
    __syncthreads();
    if (ks + 1 < CH / 32) {
      int kc = (ks + 1) * 32 + scol;
      ra[0] = ld8_cvt(X, (size_t)arow0 * CH + kc, f32);
      ra[1] = ld8_cvt(X, (size_t)arow1 * CH + kc, f32);
      rb[0] = ld8_cvt(W, (size_t)brow0 * CH + kc, f32);
      rb[1] = ld8_cvt(W, (size_t)brow1 * CH + kc, f32);
    }
    f16x8 af[4], bf_[4];
    #pragma unroll
    for (int i = 0; i < 4; ++i)
      af[i] = *(const f16x8*)&As[(wm * 64 + i * 16 + l16) * LDP + quad * 8];
    #pragma unroll
    for (int j = 0; j < 4; ++j)
      bf_[j] = *(const f16x8*)&Bs[(wo * 64 + j * 16 + l16) * LDP + quad * 8];
    #pragma unroll
    for (int i = 0; i < 4; ++i)
      #pragma unroll
      for (int j = 0; j < 4; ++j)
        acc[i][j] = MFMA16(af[i], bf_[j], acc[i][j]);
  }

  #pragma unroll
  for (int i = 0; i < 4; ++i) {
    #pragma unroll
    for (int rr = 0; rr < 4; ++rr) {
      int m = m0 + wm * 64 + i * 16 + quad * 4 + rr;
      if (m >= M_ROWS) continue;
      int b = m / NTOK, n = m - b * NTOK;
      #pragma unroll
      for (int j = 0; j < 4; ++j) {
        int o = o0loc + wo * 64 + j * 16 + l16;
        int h = o >> 6, dd = o & 63;
        _Float16 val = (_Float16)acc[i][j][rr];
        if (t == 0)
          q[((size_t)(b * NH + h) * NTOK + n) * HD + dd] = val;
        else if (t == 1)
          k[((size_t)(b * NH + h) * NTOK + n) * HD + dd] = val;
        else
          vT[((size_t)(b * NH + h) * HD + dd) * MPV + n] = val;
      }
    }
  }
}

// ---- zero the m-pad of vT (m in [577,640)).
__global__ void zerofill_vt(_Float16* __restrict__ vT) {
  int idx = blockIdx.x * 256 + threadIdx.x;
  int r = idx >> 6, c = idx & 63;
  if (r < 16 * NH * HD && c < MPV - NTOK)
    vT[(size_t)r * MPV + NTOK + c] = (_Float16)0.f;
}

// ---- Kernel 2: QK^T + Wpre mix + exp -> E (unnormalized) + PARTIAL ROWSUMS.
// The Es LDS tile already holds this block's 64 m-cols; summing them here
// (192 threads, 8 f16x8 LDS reads each) removes pv_mix's entire phase A
// (a 145 MB latency-bound E re-read).
__global__ __launch_bounds__(256) void qk_exp(
    const _Float16* __restrict__ q, const _Float16* __restrict__ k,
    const void* __restrict__ Wpre, const int* __restrict__ flagp,
    _Float16* __restrict__ E, float* __restrict__ Rp, int b0)
{
  const bool f32 = (*flagp != 0);
  __shared__ float wp[NH * NH];
  __shared__ _Float16 Es[NH * 16 * ESP];   // [g][n(16)][m(64)], pitch 72
  const int tid = threadIdx.x;
  if (tid < NH * NH) wp[tid] = ldin(Wpre, tid, f32) * 0.125f;  // fold scale
  __syncthreads();
  const int lane = tid & 63, wave = tid >> 6;
  const int quad = lane >> 4, l16 = lane & 15;
  const int bl = blockIdx.z, b = b0 + bl;
  const int n0 = blockIdx.y * 16;
  const int bx = blockIdx.x;
  const int m0 = bx * 64 + wave * 16;
  const int nq = min(n0 + l16, NTOK - 1);
  const int mk = min(m0 + l16, NTOK - 1);
  const size_t qbase = ((size_t)b * NH * NTOK + nq) * HD + quad * 8;
  const size_t kbase = ((size_t)b * NH * NTOK + mk) * HD + quad * 8;
  f32x4 acc[NH];
  #pragma unroll
  for (int h = 0; h < NH; ++h) {
    const size_t ho = (size_t)h * NTOK * HD;
    f16x8 a0 = *(const f16x8*)(q + qbase + ho);
    f16x8 bb0 = *(const f16x8*)(k + kbase + ho);
    f16x8 a1 = *(const f16x8*)(q + qbase + ho + 32);
    f16x8 bb1 = *(const f16x8*)(k + kbase + ho + 32);
    f32x4 z = {0.f, 0.f, 0.f, 0.f};
    z = MFMA16(a0, bb0, z);
    acc[h] = MFMA16(a1, bb1, z);
  }
  const int mloc = wave * 16 + l16;          // col within 64-wide tile
  const bool valid = (m0 + l16 < NTOK);
  #pragma unroll
  for (int g = 0; g < NH; ++g) {
    float s0 = 0.f, s1 = 0.f, s2 = 0.f, s3 = 0.f;
    #pragma unroll
    for (int h = 0; h < NH; ++h) {
      float w = wp[g * NH + h];
      s0 += w * acc[h][0]; s1 += w * acc[h][1];
      s2 += w * acc[h][2]; s3 += w * acc[h][3];
    }
    Es[(g * 16 + quad * 4 + 0) * ESP + mloc] = (_Float16)(valid ? __expf(s0) : 0.f);
    Es[(g * 16 + quad * 4 + 1) * ESP + mloc] = (_Float16)(valid ? __expf(s1) : 0.f);
    Es[(g * 16 + quad * 4 + 2) * ESP + mloc] = (_Float16)(valid ? __expf(s2) : 0.f);
    Es[(g * 16 + quad * 4 + 3) * ESP + mloc] = (_Float16)(valid ? __expf(s3) : 0.f);
  }
  __syncthreads();
  // cooperative full-line store: 8 lanes x 16 B = 128 B contiguous per row
  const int sub = tid & 7;
  const int rbk = tid >> 3;                  // 32 rows per pass
  #pragma unroll
  for (int it = 0; it < 6; ++it) {
    int idx = it * 32 + rbk;                 // 0..191
    int g = idx >> 4, n = idx & 15;
    f16x8 vv = *(const f16x8*)&Es[(g * 16 + n) * ESP + sub * 8];
    *(f16x8*)&E[((size_t)(bl * NH + g) * NPAD + n0 + n) * MPV + bx * 64 + sub * 8] = vv;
  }
  // partial rowsum of this block's 64 m-cols, per (g, n): Rp[b][g][bx][n]
  if (tid < NH * 16) {
    const _Float16* row = &Es[tid * ESP];
    float tot = 0.f;
    #pragma unroll
    for (int c = 0; c < 8; ++c) {
      f16x8 t = *(const f16x8*)&row[c * 8];
      #pragma unroll
      for (int j = 0; j < 8; ++j) tot += (float)t[j];
    }
    Rp[(((size_t)b * NH + (tid >> 4)) * 10 + bx) * NPAD + n0 + (tid & 15)] = tot;
  }
}

// ---- Kernel 3 phase-B body: normalize + Wpost mix (packed f16) -> P2s,
// PV via MFMA, double-buffered E prefetch across the lgkm-only barrier.
template<int NC, int D0>
__device__ __forceinline__ void pv_phaseB(
    const _Float16* __restrict__ E, const _Float16* __restrict__ vT,
    _Float16* P2s, const _Float16* w2s, const _Float16* rloc,
    f32x4 (&O)[3][4], int bl, int b, int n0, int w, int quad, int l16, int gg0)
{
  const int swz = (l16 & 7) << 3;
  const size_t ebase = ((size_t)(bl * NH) * NPAD + n0 + l16) * MPV
                     + w * 32 + quad * 8;
  const size_t estep = (size_t)NPAD * MPV;   // per-head stride
  f16x8 ev0[NH], ev1[NH];
  #pragma unroll
  for (int h = 0; h < NH; ++h)
    ev0[h] = *(const f16x8*)&E[ebase + h * estep + D0 * 128];
  #pragma unroll
  for (int i = 0; i < NC; ++i) {
    const int dmt = D0 + i;
    f16x8* cur = (i & 1) ? ev1 : ev0;
    f16x8* nxt = (i & 1) ? ev0 : ev1;
    BAR();                                    // previous P2s readers done
    if (i + 1 < NC) {                         // prefetch next chunk (in flight
      #pragma unroll                          // across both barriers below)
      for (int h = 0; h < NH; ++h)
        nxt[h] = *(const f16x8*)&E[ebase + h * estep + (dmt + 1) * 128];
    }
    #pragma unroll
    for (int h = 0; h < NH; ++h) cur[h] *= rloc[h];
    #pragma unroll
    for (int gp = 0; gp < NH; ++gp) {
      f16x8 p = cur[0] * w2s[gp * NH + 0];
      #pragma unroll
      for (int h = 1; h < NH; ++h) p += cur[h] * w2s[gp * NH + h];
      *(f16x8*)&P2s[gp * 2048 + l16 * 128 + ((w * 32 + quad * 8) ^ swz)] = p;
    }
    BAR();
    #pragma unroll
    for (int kc = 0; kc < 4; ++kc) {
      #pragma unroll
      for (int j = 0; j < 3; ++j) {
        const int g = gg0 + j;
        f16x8 a = *(const f16x8*)&P2s[g * 2048 + l16 * 128 + ((kc * 32 + quad * 8) ^ swz)];
        #pragma unroll
        for (int dt = 0; dt < 4; ++dt) {
          f16x8 bv = *(const f16x8*)(
              vT + ((size_t)(b * NH + g) * HD + dt * 16 + l16) * MPV
                 + dmt * 128 + kc * 32 + quad * 8);
          O[j][dt] = MFMA16(a, bv, O[j][dt]);
        }
      }
    }
  }
}

// ---- Kernel 3: rowsums from Rp partials, normalize + Wpost mix + PV.
// m-split across blockIdx.z (chunks {0,1,2} / {3,4}) doubles the grid to
// 1184 blocks; partial f32 O written to Op0/Op1, summed by reduce_o1.
__global__ __launch_bounds__(256) void pv_mix2(
    const _Float16* __restrict__ E, const _Float16* __restrict__ vT,
    const float* __restrict__ Rp, const void* __restrict__ Wpost,
    const int* __restrict__ flagp, float* __restrict__ Op0,
    float* __restrict__ Op1, int b0)
{
  const bool f32 = (*flagp != 0);
  __shared__ _Float16 P2s[NH * 16 * 128];   // XOR-swizzled, pitch 128
  __shared__ _Float16 w2s[NH * NH];
  __shared__ _Float16 rinvs[NH * 16];
  const int tid = threadIdx.x;
  const int lane = tid & 63, w = tid >> 6;
  const int quad = lane >> 4, l16 = lane & 15;
  const int n0 = blockIdx.x * 16;
  const int bl = blockIdx.y, b = b0 + bl;
  const int z = blockIdx.z;
  if (tid < NH * NH) w2s[tid] = (_Float16)ldin(Wpost, tid, f32);
  if (tid < NH * 16) {
    float tot = 0.f;
    #pragma unroll
    for (int mb = 0; mb < 10; ++mb)
      tot += Rp[(((size_t)b * NH + (tid >> 4)) * 10 + mb) * NPAD + n0 + (tid & 15)];
    rinvs[tid] = (_Float16)(tot > 0.f ? 1.f / tot : 0.f);
  }
  __syncthreads();
  _Float16 rloc[NH];
  #pragma unroll
  for (int h = 0; h < NH; ++h) rloc[h] = rinvs[h * 16 + l16];

  f32x4 O[3][4];
  #pragma unroll
  for (int j = 0; j < 3; ++j)
    #pragma unroll
    for (int dt = 0; dt < 4; ++dt) O[j][dt] = (f32x4){0.f, 0.f, 0.f, 0.f};
  const int gg0 = w * 3;

  if (z == 0)
    pv_phaseB<3, 0>(E, vT, P2s, w2s, rloc, O, bl, b, n0, w, quad, l16, gg0);
  else
    pv_phaseB<2, 3>(E, vT, P2s, w2s, rloc, O, bl, b, n0, w, quad, l16, gg0);

  float* __restrict__ Op = z ? Op1 : Op0;
  #pragma unroll
  for (int j = 0; j < 3; ++j)
    #pragma unroll
    for (int dt = 0; dt < 4; ++dt)
      #pragma unroll
      for (int r = 0; r < 4; ++r) {
        int n = n0 + quad * 4 + r;
        if (n < NTOK)
          Op[((size_t)bl * NTOK + n) * CH + (gg0 + j) * HD + dt * 16 + l16] =
              O[j][dt][r];
      }
}

// ---- Kernel 3b: o1 = (f16)(Op0 + Op1)
__global__ __launch_bounds__(256) void reduce_o1(
    const float* __restrict__ Op0, const float* __restrict__ Op1,
    _Float16* __restrict__ o1, int nelem)
{
  int i = (blockIdx.x * 256 + threadIdx.x) * 8;
  if (i >= nelem) return;
  float4 a0 = *(const float4*)(Op0 + i);
  float4 a1 = *(const float4*)(Op0 + i + 4);
  float4 c0 = *(const float4*)(Op1 + i);
  float4 c1 = *(const float4*)(Op1 + i + 4);
  f16x8 r;
  r[0] = (_Float16)(a0.x + c0.x); r[1] = (_Float16)(a0.y + c0.y);
  r[2] = (_Float16)(a0.z + c0.z); r[3] = (_Float16)(a0.w + c0.w);
  r[4] = (_Float16)(a1.x + c1.x); r[5] = (_Float16)(a1.y + c1.y);
  r[6] = (_Float16)(a1.z + c1.z); r[7] = (_Float16)(a1.w + c1.w);
  *(f16x8*)(o1 + i) = r;
}

// ---- Kernel 4: out = o1 @ Wproj^T + bproj via MFMA, 128x128 tiles.
__global__ __launch_bounds__(256) void gemm_proj_mfma(
    const _Float16* __restrict__ A, const void* __restrict__ W,
    const void* __restrict__ bias, const int* __restrict__ flagp,
    void* __restrict__ out)
{
  const bool f32 = (*flagp != 0);
  __shared__ _Float16 As[128 * LDP];
  __shared__ _Float16 Bs[128 * LDP];
  const int tid = threadIdx.x;
  const int lane = tid & 63, wave = tid >> 6;
  const int quad = lane >> 4, l16 = lane & 15;
  const int wm = wave & 1, wo = wave >> 1;
  const int m0 = blockIdx.y * 128;
  const int o0 = blockIdx.x * 128;

  const int srow = tid >> 2;
  const int scol = (tid & 3) * 8;
  const int arow0 = min(m0 + srow, M_ROWS - 1);
  const int arow1 = min(m0 + srow + 64, M_ROWS - 1);
  const int brow0 = o0 + srow;
  const int brow1 = o0 + srow + 64;

  f16x8 ra[2], rb[2];
  ra[0] = *(const f16x8*)(A + (size_t)arow0 * CH + scol);
  ra[1] = *(const f16x8*)(A + (size_t)arow1 * CH + scol);
  rb[0] = ld8_cvt(W, (size_t)brow0 * CH + scol, f32);
  rb[1] = ld8_cvt(W, (size_t)brow1 * CH + scol, f32);

  f32x4 acc[4][4] = {};
  for (int ks = 0; ks < CH / 32; ++ks) {
    __syncthreads();
    *(f16x8*)&As[(srow)      * LDP + scol] = ra[0];
    *(f16x8*)&As[(srow + 64) * LDP + scol] = ra[1];
    *(f16x8*)&Bs[(srow)      * LDP + scol] = rb[0];
    *(f16x8*)&Bs[(srow + 64) * LDP + scol] = rb[1];
    __syncthreads();
    if (ks + 1 < CH / 32) {
      int kc = (ks + 1) * 32 + scol;
      ra[0] = *(const f16x8*)(A + (size_t)arow0 * CH + kc);
      ra[1] = *(const f16x8*)(A + (size_t)arow1 * CH + kc);
      rb[0] = ld8_cvt(W, (size_t)brow0 * CH + kc, f32);
      rb[1] = ld8_cvt(W, (size_t)brow1 * CH + kc, f32);
    }
    f16x8 af[4], bf_[4];
    #pragma unroll
    for (int i = 0; i < 4; ++i)
      af[i] = *(const f16x8*)&As[(wm * 64 + i * 16 + l16) * LDP + quad * 8];
    #pragma unroll
    for (int j = 0; j < 4; ++j)
      bf_[j] = *(const f16x8*)&Bs[(wo * 64 + j * 16 + l16) * LDP + quad * 8];
    #pragma unroll
    for (int i = 0; i < 4; ++i)
      #pragma unroll
      for (int j = 0; j < 4; ++j)
        acc[i][j] = MFMA16(af[i], bf_[j], acc[i][j]);
  }

  #pragma unroll
  for (int i = 0; i < 4; ++i) {
    #pragma unroll
    for (int rr = 0; rr < 4; ++rr) {
      int m = m0 + wm * 64 + i * 16 + quad * 4 + rr;
      if (m >= M_ROWS) continue;
      #pragma unroll
      for (int j = 0; j < 4; ++j) {
        int o = o0 + wo * 64 + j * 16 + l16;
        float val = acc[i][j][rr] + ldin(bias, o, f32);
        if (f32) ((float*)out)[(size_t)m * CH + o] = val;
        else ((__hip_bfloat16*)out)[(size_t)m * CH + o] = __float2bfloat16(val);
      }
    }
  }
}

extern "C" void kernel_launch(void* const* d_in, const int* in_sizes, int n_in,
                              void* d_out, int out_size, void* d_ws, size_t ws_size,
                              hipStream_t stream) {
  const void* x     = d_in[0];
  const void* Wqkv  = d_in[1];
  const void* Wproj = d_in[2];
  const void* bproj = d_in[3];
  const void* Wpre  = d_in[4];
  const void* Wpost = d_in[5];

  int* flag = (int*)d_ws;
  _Float16* ws = (_Float16*)((char*)d_ws + 16);
  const size_t QE  = (size_t)16 * NH * NTOK * HD;   // 7,090,176 (== M_ROWS*CH)
  const size_t VTE = (size_t)16 * NH * HD * MPV;    // 7,864,320
  const size_t RPE = (size_t)16 * NH * 10 * NPAD;   // 1,136,640 f32
  const size_t EPB = (size_t)NH * NPAD * MPV;       // 4,546,560 f16 per batch
  const size_t OPB = (size_t)NTOK * CH;             // 443,136 f32 per batch

  _Float16* q   = ws;
  _Float16* k   = q + QE;
  _Float16* vT  = k + QE;
  _Float16* o1  = vT + VTE;
  float*    Rp  = (float*)(o1 + QE);

  // choose batch chunk from available workspace
  const size_t fixedB = 16 + (3 * QE + VTE) * sizeof(_Float16) + RPE * sizeof(float);
  const size_t perB   = EPB * sizeof(_Float16) + 2 * OPB * sizeof(float);
  int cb = 16;
  while (cb > 1 && fixedB + (size_t)cb * perB > ws_size) cb >>= 1;

  _Float16* E   = (_Float16*)(Rp + RPE);
  float*    Op0 = (float*)(E + (size_t)cb * EPB);
  float*    Op1 = Op0 + (size_t)cb * OPB;

  dim3 blk(256);
  hipLaunchKernelGGL(detect_dtype, dim3(1), blk, 0, stream,
                     (const unsigned short*)x, flag);
  hipLaunchKernelGGL(gemm_qkv_mfma, dim3(18, 73), blk, 0, stream,
                     x, Wqkv, flag, q, k, vT);
  hipLaunchKernelGGL(zerofill_vt, dim3(16 * NH * HD * 64 / 256), blk, 0, stream, vT);
  for (int b0 = 0; b0 < 16; b0 += cb) {
    hipLaunchKernelGGL(qk_exp, dim3(10, 37, cb), blk, 0, stream,
                       q, k, Wpre, flag, E, Rp, b0);
    hipLaunchKernelGGL(pv_mix2, dim3(37, cb, 2), blk, 0, stream,
                       E, vT, Rp, Wpost, flag, Op0, Op1, b0);
    int nelem = cb * (int)OPB;
    hipLaunchKernelGGL(reduce_o1, dim3((nelem / 8 + 255) / 256), blk, 0, stream,
                       Op0, Op1, o1 + (size_t)b0 * OPB, nelem);
  }
  hipLaunchKernelGGL(gemm_proj_mfma, dim3(6, 73), blk, 0, stream,
                     o1, Wproj, bproj, flag, d_out);
}

// Round 3
// 542.810 us; speedup vs baseline: 1.4989x; 1.0769x over previous
//
#include <hip/hip_runtime.h>
#include <hip/hip_bf16.h>

#define NTOK 577
#define CH 768
#define NH 12
#define HD 64
#define M_ROWS 9232      // B * N
#define NPAD 592         // n pitch of E
#define MPV 640          // m pitch of vT and E (5 * 128)
#define LDP 40           // padded LDS row pitch (f16) for GEMM tiles
#define ESP 72           // qk_exp LDS E-tile pitch (f16): 144 B = 9*16 aligned

typedef _Float16 f16x8 __attribute__((ext_vector_type(8)));
typedef float f32x4 __attribute__((ext_vector_type(4)));

#define MFMA16(a, b, c) __builtin_amdgcn_mfma_f32_16x16x32_f16((a), (b), (c), 0, 0, 0)

// barrier that does NOT drain vmcnt (LDS deps need lgkmcnt only)
#define BAR() asm volatile("s_waitcnt lgkmcnt(0)\n\ts_barrier" ::: "memory")

// XCD-chunked bijective swizzle (m204): blocks with consecutive returned ids
// share lin%8 == same XCD -> data-sharing neighbors hit the same L2.
__device__ __forceinline__ int xcd_swz(int lin, int G) {
  int q = G >> 3, r = G & 7;
  int x = lin & 7, i = lin >> 3;
  return (x < r ? x * (q + 1) : r * (q + 1) + (x - r) * q) + i;
}

__device__ __forceinline__ float bf2f(unsigned int u16) {
  union { unsigned int i; float f; } x; x.i = u16 << 16; return x.f;
}

__device__ __forceinline__ float ldin(const void* p, size_t i, bool f32) {
  return f32 ? ((const float*)p)[i]
             : __bfloat162float(((const __hip_bfloat16*)p)[i]);
}

__device__ __forceinline__ f16x8 ld8_cvt(const void* p, size_t idx, bool f32) {
  f16x8 r;
  if (f32) {
    const float* f = (const float*)p + idx;
    const float4 u = *(const float4*)f;
    const float4 v = *(const float4*)(f + 4);
    r[0]=(_Float16)u.x; r[1]=(_Float16)u.y; r[2]=(_Float16)u.z; r[3]=(_Float16)u.w;
    r[4]=(_Float16)v.x; r[5]=(_Float16)v.y; r[6]=(_Float16)v.z; r[7]=(_Float16)v.w;
  } else {
    const unsigned short* s = (const unsigned short*)p + idx;
    uint4 u = *(const uint4*)s;
    unsigned int w0=u.x, w1=u.y, w2=u.z, w3=u.w;
    r[0]=(_Float16)bf2f(w0&0xffffu); r[1]=(_Float16)bf2f(w0>>16);
    r[2]=(_Float16)bf2f(w1&0xffffu); r[3]=(_Float16)bf2f(w1>>16);
    r[4]=(_Float16)bf2f(w2&0xffffu); r[5]=(_Float16)bf2f(w2>>16);
    r[6]=(_Float16)bf2f(w3&0xffffu); r[7]=(_Float16)bf2f(w3>>16);
  }
  return r;
}

// ---- Kernel 0: detect input dtype (fp32 vs bf16).
__global__ void detect_dtype(const unsigned short* __restrict__ xs,
                             int* __restrict__ flag) {
  __shared__ int cnt;
  if (threadIdx.x == 0) cnt = 0;
  __syncthreads();
  int local = 0;
  for (int i = threadIdx.x; i < 4096; i += 256) {
    unsigned int u = xs[2 * i];
    unsigned int e = (u >> 7) & 0xFFu;
    if (e >= 140u) local++;
  }
  atomicAdd(&cnt, local);
  __syncthreads();
  if (threadIdx.x == 0) *flag = (cnt > 100) ? 1 : 0;
}

// ---- Kernel 0b: convert an fp32/bf16 array to f16 (one rounding — the GEMM
// previously rounded to f16 per-use anyway, so numerics are identical).
__global__ __launch_bounds__(256) void cvt_f16(
    const void* __restrict__ in, _Float16* __restrict__ outp,
    const int* __restrict__ flagp, int n8)
{
  const bool f32 = (*flagp != 0);
  int i = blockIdx.x * 256 + threadIdx.x;
  if (i < n8) *(f16x8*)(outp + (size_t)i * 8) = ld8_cvt(in, (size_t)i * 8, f32);
}

// ---- Kernel 1: qkv = x @ Wqkv^T via MFMA 16x16x32 f16, 128x128 tiles.
// All-f16 inputs; 1D grid + XCD swizzle (18 n-blocks sharing an X tile sit
// on one XCD -> X fetched ~once per XCD instead of ~5x; round-2 FETCH=140MB).
__global__ __launch_bounds__(256) void gemm_qkv_mfma(
    const _Float16* __restrict__ X, const _Float16* __restrict__ W,
    _Float16* __restrict__ q, _Float16* __restrict__ k,
    _Float16* __restrict__ vT)
{
  __shared__ _Float16 As[128 * LDP];
  __shared__ _Float16 Bs[128 * LDP];
  const int swz = xcd_swz(blockIdx.x, 18 * 73);
  const int bx = swz % 18;                 // output-col tile (fast: shares X)
  const int m0 = (swz / 18) * 128;
  const int tid = threadIdx.x;
  const int lane = tid & 63, wave = tid >> 6;
  const int quad = lane >> 4, l16 = lane & 15;
  const int wm = wave & 1, wo = wave >> 1;
  const int t = bx / 6;                    // 0=q 1=k 2=v
  const int o0 = bx * 128;
  const int o0loc = o0 - t * CH;

  const int srow = tid >> 2;
  const int scol = (tid & 3) * 8;
  const int arow0 = min(m0 + srow, M_ROWS - 1);
  const int arow1 = min(m0 + srow + 64, M_ROWS - 1);
  const int brow0 = o0 + srow;
  const int brow1 = o0 + srow + 64;

  f16x8 ra[2], rb[2];
  ra[0] = *(const f16x8*)(X + (size_t)arow0 * CH + scol);
  ra[1] = *(const f16x8*)(X + (size_t)arow1 * CH + scol);
  rb[0] = *(const f16x8*)(W + (size_t)brow0 * CH + scol);
  rb[1] = *(const f16x8*)(W + (size_t)brow1 * CH + scol);

  f32x4 acc[4][4] = {};
  for (int ks = 0; ks < CH / 32; ++ks) {
    __syncthreads();
    *(f16x8*)&As[(srow)      * LDP + scol] = ra[0];
    *(f16x8*)&As[(srow + 64) * LDP + scol] = ra[1];
    *(f16x8*)&Bs[(srow)      * LDP + scol] = rb[0];
    *(f16x8*)&Bs[(srow + 64) * LDP + scol] = rb[1];
    __syncthreads();
    if (ks + 1 < CH / 32) {
      int kc = (ks + 1) * 32 + scol;
      ra[0] = *(const f16x8*)(X + (size_t)arow0 * CH + kc);
      ra[1] = *(const f16x8*)(X + (size_t)arow1 * CH + kc);
      rb[0] = *(const f16x8*)(W + (size_t)brow0 * CH + kc);
      rb[1] = *(const f16x8*)(W + (size_t)brow1 * CH + kc);
    }
    f16x8 af[4], bf_[4];
    #pragma unroll
    for (int i = 0; i < 4; ++i)
      af[i] = *(const f16x8*)&As[(wm * 64 + i * 16 + l16) * LDP + quad * 8];
    #pragma unroll
    for (int j = 0; j < 4; ++j)
      bf_[j] = *(const f16x8*)&Bs[(wo * 64 + j * 16 + l16) * LDP + quad * 8];
    #pragma unroll
    for (int i = 0; i < 4; ++i)
      #pragma unroll
      for (int j = 0; j < 4; ++j)
        acc[i][j] = MFMA16(af[i], bf_[j], acc[i][j]);
  }

  #pragma unroll
  for (int i = 0; i < 4; ++i) {
    #pragma unroll
    for (int rr = 0; rr < 4; ++rr) {
      int m = m0 + wm * 64 + i * 16 + quad * 4 + rr;
      if (m >= M_ROWS) continue;
      int b = m / NTOK, n = m - b * NTOK;
      #pragma unroll
      for (int j = 0; j < 4; ++j) {
        int o = o0loc + wo * 64 + j * 16 + l16;
        int h = o >> 6, dd = o & 63;
        _Float16 val = (_Float16)acc[i][j][rr];
        if (t == 0)
          q[((size_t)(b * NH + h) * NTOK + n) * HD + dd] = val;
        else if (t == 1)
          k[((size_t)(b * NH + h) * NTOK + n) * HD + dd] = val;
        else
          vT[((size_t)(b * NH + h) * HD + dd) * MPV + n] = val;
      }
    }
  }
}

// ---- zero the m-pad of vT (m in [577,640)).
__global__ void zerofill_vt(_Float16* __restrict__ vT) {
  int idx = blockIdx.x * 256 + threadIdx.x;
  int r = idx >> 6, c = idx & 63;
  if (r < 16 * NH * HD && c < MPV - NTOK)
    vT[(size_t)r * MPV + NTOK + c] = (_Float16)0.f;
}

// ---- Kernel 2: QK^T + Wpre mix + exp -> E (unnormalized) + partial rowsums.
// 1D grid + XCD swizzle: all blocks of one batch contiguous -> that batch's
// q/k stay in one XCD's L2.
__global__ __launch_bounds__(256) void qk_exp(
    const _Float16* __restrict__ q, const _Float16* __restrict__ k,
    const void* __restrict__ Wpre, const int* __restrict__ flagp,
    _Float16* __restrict__ E, float* __restrict__ Rp, int b0, int cb)
{
  const bool f32 = (*flagp != 0);
  __shared__ float wp[NH * NH];
  __shared__ _Float16 Es[NH * 16 * ESP];   // [g][n(16)][m(64)], pitch 72
  const int tid = threadIdx.x;
  if (tid < NH * NH) wp[tid] = ldin(Wpre, tid, f32) * 0.125f;  // fold scale
  __syncthreads();
  const int swz = xcd_swz(blockIdx.x, 370 * cb);
  const int bl = swz / 370;
  const int ny = (swz % 370) / 10;
  const int bx = swz % 10;
  const int lane = tid & 63, wave = tid >> 6;
  const int quad = lane >> 4, l16 = lane & 15;
  const int b = b0 + bl;
  const int n0 = ny * 16;
  const int m0 = bx * 64 + wave * 16;
  const int nq = min(n0 + l16, NTOK - 1);
  const int mk = min(m0 + l16, NTOK - 1);
  const size_t qbase = ((size_t)b * NH * NTOK + nq) * HD + quad * 8;
  const size_t kbase = ((size_t)b * NH * NTOK + mk) * HD + quad * 8;
  f32x4 acc[NH];
  #pragma unroll
  for (int h = 0; h < NH; ++h) {
    const size_t ho = (size_t)h * NTOK * HD;
    f16x8 a0 = *(const f16x8*)(q + qbase + ho);
    f16x8 bb0 = *(const f16x8*)(k + kbase + ho);
    f16x8 a1 = *(const f16x8*)(q + qbase + ho + 32);
    f16x8 bb1 = *(const f16x8*)(k + kbase + ho + 32);
    f32x4 z = {0.f, 0.f, 0.f, 0.f};
    z = MFMA16(a0, bb0, z);
    acc[h] = MFMA16(a1, bb1, z);
  }
  const int mloc = wave * 16 + l16;          // col within 64-wide tile
  const bool valid = (m0 + l16 < NTOK);
  #pragma unroll
  for (int g = 0; g < NH; ++g) {
    float s0 = 0.f, s1 = 0.f, s2 = 0.f, s3 = 0.f;
    #pragma unroll
    for (int h = 0; h < NH; ++h) {
      float w = wp[g * NH + h];
      s0 += w * acc[h][0]; s1 += w * acc[h][1];
      s2 += w * acc[h][2]; s3 += w * acc[h][3];
    }
    Es[(g * 16 + quad * 4 + 0) * ESP + mloc] = (_Float16)(valid ? __expf(s0) : 0.f);
    Es[(g * 16 + quad * 4 + 1) * ESP + mloc] = (_Float16)(valid ? __expf(s1) : 0.f);
    Es[(g * 16 + quad * 4 + 2) * ESP + mloc] = (_Float16)(valid ? __expf(s2) : 0.f);
    Es[(g * 16 + quad * 4 + 3) * ESP + mloc] = (_Float16)(valid ? __expf(s3) : 0.f);
  }
  __syncthreads();
  // cooperative full-line store: 8 lanes x 16 B = 128 B contiguous per row
  const int sub = tid & 7;
  const int rbk = tid >> 3;                  // 32 rows per pass
  #pragma unroll
  for (int it = 0; it < 6; ++it) {
    int idx = it * 32 + rbk;                 // 0..191
    int g = idx >> 4, n = idx & 15;
    f16x8 vv = *(const f16x8*)&Es[(g * 16 + n) * ESP + sub * 8];
    *(f16x8*)&E[((size_t)(bl * NH + g) * NPAD + n0 + n) * MPV + bx * 64 + sub * 8] = vv;
  }
  // partial rowsum of this block's 64 m-cols, per (g, n): Rp[b][g][bx][n]
  if (tid < NH * 16) {
    const _Float16* row = &Es[tid * ESP];
    float tot = 0.f;
    #pragma unroll
    for (int c = 0; c < 8; ++c) {
      f16x8 t = *(const f16x8*)&row[c * 8];
      #pragma unroll
      for (int j = 0; j < 8; ++j) tot += (float)t[j];
    }
    Rp[(((size_t)b * NH + (tid >> 4)) * 10 + bx) * NPAD + n0 + (tid & 15)] = tot;
  }
}

// ---- Kernel 3 phase-B body: normalize + Wpost mix (packed f16) -> P2s,
// PV via MFMA, double-buffered E prefetch across the lgkm-only barrier.
template<int NC, int D0>
__device__ __forceinline__ void pv_phaseB(
    const _Float16* __restrict__ E, const _Float16* __restrict__ vT,
    _Float16* P2s, const _Float16* w2s, const _Float16* rloc,
    f32x4 (&O)[3][4], int bl, int b, int n0, int w, int quad, int l16, int gg0)
{
  const int swz = (l16 & 7) << 3;
  const size_t ebase = ((size_t)(bl * NH) * NPAD + n0 + l16) * MPV
                     + w * 32 + quad * 8;
  const size_t estep = (size_t)NPAD * MPV;   // per-head stride
  f16x8 ev0[NH], ev1[NH];
  #pragma unroll
  for (int h = 0; h < NH; ++h)
    ev0[h] = *(const f16x8*)&E[ebase + h * estep + D0 * 128];
  #pragma unroll
  for (int i = 0; i < NC; ++i) {
    const int dmt = D0 + i;
    f16x8* cur = (i & 1) ? ev1 : ev0;
    f16x8* nxt = (i & 1) ? ev0 : ev1;
    BAR();                                    // previous P2s readers done
    if (i + 1 < NC) {                         // prefetch next chunk (in flight
      #pragma unroll                          // across both barriers below)
      for (int h = 0; h < NH; ++h)
        nxt[h] = *(const f16x8*)&E[ebase + h * estep + (dmt + 1) * 128];
    }
    #pragma unroll
    for (int h = 0; h < NH; ++h) cur[h] *= rloc[h];
    #pragma unroll
    for (int gp = 0; gp < NH; ++gp) {
      f16x8 p = cur[0] * w2s[gp * NH + 0];
      #pragma unroll
      for (int h = 1; h < NH; ++h) p += cur[h] * w2s[gp * NH + h];
      *(f16x8*)&P2s[gp * 2048 + l16 * 128 + ((w * 32 + quad * 8) ^ swz)] = p;
    }
    BAR();
    #pragma unroll
    for (int kc = 0; kc < 4; ++kc) {
      #pragma unroll
      for (int j = 0; j < 3; ++j) {
        const int g = gg0 + j;
        f16x8 a = *(const f16x8*)&P2s[g * 2048 + l16 * 128 + ((kc * 32 + quad * 8) ^ swz)];
        #pragma unroll
        for (int dt = 0; dt < 4; ++dt) {
          f16x8 bv = *(const f16x8*)(
              vT + ((size_t)(b * NH + g) * HD + dt * 16 + l16) * MPV
                 + dmt * 128 + kc * 32 + quad * 8);
          O[j][dt] = MFMA16(a, bv, O[j][dt]);
        }
      }
    }
  }
}

// ---- Kernel 3: rowsums from Rp partials, normalize + Wpost mix + PV.
// m-split across z (chunks {0,1,2} / {3,4}); 1D grid + XCD swizzle.
__global__ __launch_bounds__(256) void pv_mix2(
    const _Float16* __restrict__ E, const _Float16* __restrict__ vT,
    const float* __restrict__ Rp, const void* __restrict__ Wpost,
    const int* __restrict__ flagp, float* __restrict__ Op0,
    float* __restrict__ Op1, int b0, int cb)
{
  const bool f32 = (*flagp != 0);
  __shared__ _Float16 P2s[NH * 16 * 128];   // XOR-swizzled, pitch 128
  __shared__ _Float16 w2s[NH * NH];
  __shared__ _Float16 rinvs[NH * 16];
  const int swz = xcd_swz(blockIdx.x, 74 * cb);
  const int bl = swz / 74;
  const int z = (swz % 74) / 37;
  const int nx = swz % 37;
  const int tid = threadIdx.x;
  const int lane = tid & 63, w = tid >> 6;
  const int quad = lane >> 4, l16 = lane & 15;
  const int n0 = nx * 16;
  const int b = b0 + bl;
  if (tid < NH * NH) w2s[tid] = (_Float16)ldin(Wpost, tid, f32);
  if (tid < NH * 16) {
    float tot = 0.f;
    #pragma unroll
    for (int mb = 0; mb < 10; ++mb)
      tot += Rp[(((size_t)b * NH + (tid >> 4)) * 10 + mb) * NPAD + n0 + (tid & 15)];
    rinvs[tid] = (_Float16)(tot > 0.f ? 1.f / tot : 0.f);
  }
  __syncthreads();
  _Float16 rloc[NH];
  #pragma unroll
  for (int h = 0; h < NH; ++h) rloc[h] = rinvs[h * 16 + l16];

  f32x4 O[3][4];
  #pragma unroll
  for (int j = 0; j < 3; ++j)
    #pragma unroll
    for (int dt = 0; dt < 4; ++dt) O[j][dt] = (f32x4){0.f, 0.f, 0.f, 0.f};
  const int gg0 = w * 3;

  if (z == 0)
    pv_phaseB<3, 0>(E, vT, P2s, w2s, rloc, O, bl, b, n0, w, quad, l16, gg0);
  else
    pv_phaseB<2, 3>(E, vT, P2s, w2s, rloc, O, bl, b, n0, w, quad, l16, gg0);

  float* __restrict__ Op = z ? Op1 : Op0;
  #pragma unroll
  for (int j = 0; j < 3; ++j)
    #pragma unroll
    for (int dt = 0; dt < 4; ++dt)
      #pragma unroll
      for (int r = 0; r < 4; ++r) {
        int n = n0 + quad * 4 + r;
        if (n < NTOK)
          Op[((size_t)bl * NTOK + n) * CH + (gg0 + j) * HD + dt * 16 + l16] =
              O[j][dt][r];
      }
}

// ---- Kernel 3b: o1 = (f16)(Op0 + Op1)
__global__ __launch_bounds__(256) void reduce_o1(
    const float* __restrict__ Op0, const float* __restrict__ Op1,
    _Float16* __restrict__ o1, int nelem)
{
  int i = (blockIdx.x * 256 + threadIdx.x) * 8;
  if (i >= nelem) return;
  float4 a0 = *(const float4*)(Op0 + i);
  float4 a1 = *(const float4*)(Op0 + i + 4);
  float4 c0 = *(const float4*)(Op1 + i);
  float4 c1 = *(const float4*)(Op1 + i + 4);
  f16x8 r;
  r[0] = (_Float16)(a0.x + c0.x); r[1] = (_Float16)(a0.y + c0.y);
  r[2] = (_Float16)(a0.z + c0.z); r[3] = (_Float16)(a0.w + c0.w);
  r[4] = (_Float16)(a1.x + c1.x); r[5] = (_Float16)(a1.y + c1.y);
  r[6] = (_Float16)(a1.z + c1.z); r[7] = (_Float16)(a1.w + c1.w);
  *(f16x8*)(o1 + i) = r;
}

// ---- Kernel 4: out = o1 @ Wproj^T + bproj via MFMA, 128x128 tiles.
__global__ __launch_bounds__(256) void gemm_proj_mfma(
    const _Float16* __restrict__ A, const _Float16* __restrict__ W,
    const void* __restrict__ bias, const int* __restrict__ flagp,
    void* __restrict__ out)
{
  const bool f32 = (*flagp != 0);
  __shared__ _Float16 As[128 * LDP];
  __shared__ _Float16 Bs[128 * LDP];
  const int swz = xcd_swz(blockIdx.x, 6 * 73);
  const int o0 = (swz % 6) * 128;
  const int m0 = (swz / 6) * 128;
  const int tid = threadIdx.x;
  const int lane = tid & 63, wave = tid >> 6;
  const int quad = lane >> 4, l16 = lane & 15;
  const int wm = wave & 1, wo = wave >> 1;

  const int srow = tid >> 2;
  const int scol = (tid & 3) * 8;
  const int arow0 = min(m0 + srow, M_ROWS - 1);
  const int arow1 = min(m0 + srow + 64, M_ROWS - 1);
  const int brow0 = o0 + srow;
  const int brow1 = o0 + srow + 64;

  f16x8 ra[2], rb[2];
  ra[0] = *(const f16x8*)(A + (size_t)arow0 * CH + scol);
  ra[1] = *(const f16x8*)(A + (size_t)arow1 * CH + scol);
  rb[0] = *(const f16x8*)(W + (size_t)brow0 * CH + scol);
  rb[1] = *(const f16x8*)(W + (size_t)brow1 * CH + scol);

  f32x4 acc[4][4] = {};
  for (int ks = 0; ks < CH / 32; ++ks) {
    __syncthreads();
    *(f16x8*)&As[(srow)      * LDP + scol] = ra[0];
    *(f16x8*)&As[(srow + 64) * LDP + scol] = ra[1];
    *(f16x8*)&Bs[(srow)      * LDP + scol] = rb[0];
    *(f16x8*)&Bs[(srow + 64) * LDP + scol] = rb[1];
    __syncthreads();
    if (ks + 1 < CH / 32) {
      int kc = (ks + 1) * 32 + scol;
      ra[0] = *(const f16x8*)(A + (size_t)arow0 * CH + kc);
      ra[1] = *(const f16x8*)(A + (size_t)arow1 * CH + kc);
      rb[0] = *(const f16x8*)(W + (size_t)brow0 * CH + kc);
      rb[1] = *(const f16x8*)(W + (size_t)brow1 * CH + kc);
    }
    f16x8 af[4], bf_[4];
    #pragma unroll
    for (int i = 0; i < 4; ++i)
      af[i] = *(const f16x8*)&As[(wm * 64 + i * 16 + l16) * LDP + quad * 8];
    #pragma unroll
    for (int j = 0; j < 4; ++j)
      bf_[j] = *(const f16x8*)&Bs[(wo * 64 + j * 16 + l16) * LDP + quad * 8];
    #pragma unroll
    for (int i = 0; i < 4; ++i)
      #pragma unroll
      for (int j = 0; j < 4; ++j)
        acc[i][j] = MFMA16(af[i], bf_[j], acc[i][j]);
  }

  #pragma unroll
  for (int i = 0; i < 4; ++i) {
    #pragma unroll
    for (int rr = 0; rr < 4; ++rr) {
      int m = m0 + wm * 64 + i * 16 + quad * 4 + rr;
      if (m >= M_ROWS) continue;
      #pragma unroll
      for (int j = 0; j < 4; ++j) {
        int o = o0 + wo * 64 + j * 16 + l16;
        float val = acc[i][j][rr] + ldin(bias, o, f32);
        if (f32) ((float*)out)[(size_t)m * CH + o] = val;
        else ((__hip_bfloat16*)out)[(size_t)m * CH + o] = __float2bfloat16(val);
      }
    }
  }
}

extern "C" void kernel_launch(void* const* d_in, const int* in_sizes, int n_in,
                              void* d_out, int out_size, void* d_ws, size_t ws_size,
                              hipStream_t stream) {
  const void* x     = d_in[0];
  const void* Wqkv  = d_in[1];
  const void* Wproj = d_in[2];
  const void* bproj = d_in[3];
  const void* Wpre  = d_in[4];
  const void* Wpost = d_in[5];

  int* flag = (int*)d_ws;
  _Float16* ws = (_Float16*)((char*)d_ws + 16);
  const size_t XHE = (size_t)M_ROWS * CH;           // 7,090,176
  const size_t WQH = (size_t)3 * CH * CH;           // 1,769,472
  const size_t WPH = (size_t)CH * CH;               //   589,824
  const size_t QE  = (size_t)16 * NH * NTOK * HD;   // 7,090,176
  const size_t VTE = (size_t)16 * NH * HD * MPV;    // 7,864,320
  const size_t RPE = (size_t)16 * NH * 10 * NPAD;   // 1,136,640 f32
  const size_t EPB = (size_t)NH * NPAD * MPV;       // 4,546,560 f16 per batch
  const size_t OPB = (size_t)NTOK * CH;             //   443,136 f32 per batch

  _Float16* Xh  = ws;
  _Float16* Wqh = Xh + XHE;
  _Float16* Wph = Wqh + WQH;
  _Float16* q   = Wph + WPH;
  _Float16* k   = q + QE;
  _Float16* vT  = k + QE;
  _Float16* o1  = vT + VTE;
  float*    Rp  = (float*)(o1 + QE);

  // choose batch chunk from available workspace
  const size_t fixedB = 16 + (XHE + WQH + WPH + 3 * QE + VTE) * sizeof(_Float16)
                      + RPE * sizeof(float);
  const size_t perB   = EPB * sizeof(_Float16) + 2 * OPB * sizeof(float);
  int cb = 16;
  while (cb > 1 && fixedB + (size_t)cb * perB > ws_size) cb >>= 1;

  _Float16* E   = (_Float16*)(Rp + RPE);
  float*    Op0 = (float*)(E + (size_t)cb * EPB);
  float*    Op1 = Op0 + (size_t)cb * OPB;

  dim3 blk(256);
  hipLaunchKernelGGL(detect_dtype, dim3(1), blk, 0, stream,
                     (const unsigned short*)x, flag);
  hipLaunchKernelGGL(cvt_f16, dim3((int)(XHE / 8 + 255) / 256), blk, 0, stream,
                     x, Xh, flag, (int)(XHE / 8));
  hipLaunchKernelGGL(cvt_f16, dim3((int)(WQH / 8 + 255) / 256), blk, 0, stream,
                     Wqkv, Wqh, flag, (int)(WQH / 8));
  hipLaunchKernelGGL(cvt_f16, dim3((int)(WPH / 8 + 255) / 256), blk, 0, stream,
                     Wproj, Wph, flag, (int)(WPH / 8));
  hipLaunchKernelGGL(gemm_qkv_mfma, dim3(18 * 73), blk, 0, stream,
                     Xh, Wqh, q, k, vT);
  hipLaunchKernelGGL(zerofill_vt, dim3(16 * NH * HD * 64 / 256), blk, 0, stream, vT);
  for (int b0 = 0; b0 < 16; b0 += cb) {
    hipLaunchKernelGGL(qk_exp, dim3(370 * cb), blk, 0, stream,
                       q, k, Wpre, flag, E, Rp, b0, cb);
    hipLaunchKernelGGL(pv_mix2, dim3(74 * cb), blk, 0, stream,
                       E, vT, Rp, Wpost, flag, Op0, Op1, b0, cb);
    int nelem = cb * (int)OPB;
    hipLaunchKernelGGL(reduce_o1, dim3((nelem / 8 + 255) / 256), blk, 0, stream,
                       Op0, Op1, o1 + (size_t)b0 * OPB, nelem);
  }
  hipLaunchKernelGGL(gemm_proj_mfma, dim3(6 * 73), blk, 0, stream,
                     o1, Wproj == nullptr ? nullptr : Wph, bproj, flag, d_out);
}

// Round 4
// 531.356 us; speedup vs baseline: 1.5312x; 1.0216x over previous
//
#include <hip/hip_runtime.h>
#include <hip/hip_bf16.h>

#define NTOK 577
#define CH 768
#define NH 12
#define HD 64
#define M_ROWS 9232      // B * N
#define NPAD 592         // n pitch of E
#define MPV 640          // m pitch of vT and E (5 * 128)
#define ESP 72           // qk_exp LDS E-tile pitch (f16): 144 B = 9*16 aligned

#define XHE 7090176      // M_ROWS * CH
#define WQH 1769472      // 3 * CH * CH
#define WPH 589824       // CH * CH

typedef _Float16 f16x8 __attribute__((ext_vector_type(8)));
typedef _Float16 f16x4 __attribute__((ext_vector_type(4)));
typedef _Float16 f16x2 __attribute__((ext_vector_type(2)));
typedef float f32x4 __attribute__((ext_vector_type(4)));

#define MFMA16(a, b, c) __builtin_amdgcn_mfma_f32_16x16x32_f16((a), (b), (c), 0, 0, 0)

// barrier that does NOT drain vmcnt (LDS deps need lgkmcnt only)
#define BAR() asm volatile("s_waitcnt lgkmcnt(0)\n\ts_barrier" ::: "memory")

// async global->LDS, 16 B per lane. LDS dest must be wave-linear (base+lane*16).
#define GLD16(gp, lp) __builtin_amdgcn_global_load_lds(               \
    (const __attribute__((address_space(1))) void*)(gp),              \
    (__attribute__((address_space(3))) void*)(lp), 16, 0, 0)

// XCD-chunked bijective swizzle (m204)
__device__ __forceinline__ int xcd_swz(int lin, int G) {
  int q = G >> 3, r = G & 7;
  int x = lin & 7, i = lin >> 3;
  return (x < r ? x * (q + 1) : r * (q + 1) + (x - r) * q) + i;
}

__device__ __forceinline__ float bf2f(unsigned int u16) {
  union { unsigned int i; float f; } x; x.i = u16 << 16; return x.f;
}

__device__ __forceinline__ float ldin(const void* p, size_t i, bool f32) {
  return f32 ? ((const float*)p)[i]
             : __bfloat162float(((const __hip_bfloat16*)p)[i]);
}

__device__ __forceinline__ f16x8 ld8_cvt(const void* p, size_t idx, bool f32) {
  f16x8 r;
  if (f32) {
    const float* f = (const float*)p + idx;
    const float4 u = *(const float4*)f;
    const float4 v = *(const float4*)(f + 4);
    r[0]=(_Float16)u.x; r[1]=(_Float16)u.y; r[2]=(_Float16)u.z; r[3]=(_Float16)u.w;
    r[4]=(_Float16)v.x; r[5]=(_Float16)v.y; r[6]=(_Float16)v.z; r[7]=(_Float16)v.w;
  } else {
    const unsigned short* s = (const unsigned short*)p + idx;
    uint4 u = *(const uint4*)s;
    unsigned int w0=u.x, w1=u.y, w2=u.z, w3=u.w;
    r[0]=(_Float16)bf2f(w0&0xffffu); r[1]=(_Float16)bf2f(w0>>16);
    r[2]=(_Float16)bf2f(w1&0xffffu); r[3]=(_Float16)bf2f(w1>>16);
    r[4]=(_Float16)bf2f(w2&0xffffu); r[5]=(_Float16)bf2f(w2>>16);
    r[6]=(_Float16)bf2f(w3&0xffffu); r[7]=(_Float16)bf2f(w3>>16);
  }
  return r;
}

// ---- Kernel 0: detect input dtype (fp32 vs bf16).
__global__ void detect_dtype(const unsigned short* __restrict__ xs,
                             int* __restrict__ flag) {
  __shared__ int cnt;
  if (threadIdx.x == 0) cnt = 0;
  __syncthreads();
  int local = 0;
  for (int i = threadIdx.x; i < 4096; i += 256) {
    unsigned int u = xs[2 * i];
    unsigned int e = (u >> 7) & 0xFFu;
    if (e >= 140u) local++;
  }
  atomicAdd(&cnt, local);
  __syncthreads();
  if (threadIdx.x == 0) *flag = (cnt > 100) ? 1 : 0;
}

// ---- Kernel 0b: convert x | Wqkv | Wproj into one contiguous f16 region.
__global__ __launch_bounds__(256) void cvt_all(
    const void* __restrict__ x, const void* __restrict__ wq,
    const void* __restrict__ wp, _Float16* __restrict__ dst,
    const int* __restrict__ flagp)
{
  const bool f32 = (*flagp != 0);
  size_t i = (size_t)(blockIdx.x * 256 + threadIdx.x) * 8;
  if (i >= (size_t)(XHE + WQH + WPH)) return;
  const void* src; size_t off;
  if (i < XHE)            { src = x;  off = i; }
  else if (i < XHE + WQH) { src = wq; off = i - XHE; }
  else                    { src = wp; off = i - XHE - WQH; }
  *(f16x8*)(dst + i) = ld8_cvt(src, off, f32);
}

// ---- Kernel 1: qkv = x @ Wqkv^T, m97 structure: global_load_lds width-16
// into linear [128][32] double-buffered LDS. Source-side XOR swizzle
// (chunk ^= (row>>1)&3) => ds_read_b128 16B-aligned and ~conflict-free
// (round-3: LDP=40 pitch made every b128 misaligned; 8.07M conflicts).
__global__ __launch_bounds__(256) void gemm_qkv_mfma(
    const _Float16* __restrict__ X, const _Float16* __restrict__ W,
    _Float16* __restrict__ q, _Float16* __restrict__ k,
    _Float16* __restrict__ vT)
{
  __shared__ __align__(16) _Float16 As[2][128 * 32];
  __shared__ __align__(16) _Float16 Bs[2][128 * 32];
  const int swz = xcd_swz(blockIdx.x, 18 * 73);
  const int bx = swz % 18;                 // output-col tile (fast: shares X)
  const int m0 = (swz / 18) * 128;
  const int tid = threadIdx.x;
  const int lane = tid & 63, wave = tid >> 6;
  const int quad = lane >> 4, l16 = lane & 15;
  const int wm = wave & 1, wo = wave >> 1;
  const int t = bx / 6;                    // 0=q 1=k 2=v
  const int o0 = bx * 128;
  const int o0loc = o0 - t * CH;

  // staging: wave covers rows [wave*32, wave*32+32), 2 issues of 16 rows
  const int row0 = wave * 32 + (lane >> 2);
  const int ch8  = (((lane & 3) ^ ((lane >> 3) & 3)) << 3);  // swizzled src col
  const int ar0 = min(m0 + row0, M_ROWS - 1);
  const int ar1 = min(m0 + row0 + 16, M_ROWS - 1);
  const int br0 = o0 + row0;
  const int br1 = o0 + row0 + 16;
  const int dl0 = wave * 1024 + lane * 8;   // linear LDS dest (f16 idx)
  const int dl1 = dl0 + 512;

  GLD16(X + (size_t)ar0 * CH + ch8, &As[0][dl0]);
  GLD16(X + (size_t)ar1 * CH + ch8, &As[0][dl1]);
  GLD16(W + (size_t)br0 * CH + ch8, &Bs[0][dl0]);
  GLD16(W + (size_t)br1 * CH + ch8, &Bs[0][dl1]);

  const int rdc = ((quad ^ ((l16 >> 1) & 3)) << 3);      // swizzled read col
  const int rdA = (wm * 64 + l16) * 32 + rdc;
  const int rdB = (wo * 64 + l16) * 32 + rdc;

  f32x4 acc[4][4] = {};
  int cur = 0;
  for (int ks = 0; ks < CH / 32; ++ks) {
    __syncthreads();                       // drains vmcnt: tile ks ready
    if (ks + 1 < CH / 32) {
      const int kc = (ks + 1) * 32 + ch8;
      const int nb = cur ^ 1;
      GLD16(X + (size_t)ar0 * CH + kc, &As[nb][dl0]);
      GLD16(X + (size_t)ar1 * CH + kc, &As[nb][dl1]);
      GLD16(W + (size_t)br0 * CH + kc, &Bs[nb][dl0]);
      GLD16(W + (size_t)br1 * CH + kc, &Bs[nb][dl1]);
    }
    f16x8 af[4], bf_[4];
    #pragma unroll
    for (int i = 0; i < 4; ++i)
      af[i] = *(const f16x8*)&As[cur][rdA + i * 512];
    #pragma unroll
    for (int j = 0; j < 4; ++j)
      bf_[j] = *(const f16x8*)&Bs[cur][rdB + j * 512];
    #pragma unroll
    for (int i = 0; i < 4; ++i)
      #pragma unroll
      for (int j = 0; j < 4; ++j)
        acc[i][j] = MFMA16(af[i], bf_[j], acc[i][j]);
    cur ^= 1;
  }

  if (t < 2) {
    #pragma unroll
    for (int i = 0; i < 4; ++i) {
      #pragma unroll
      for (int rr = 0; rr < 4; ++rr) {
        int m = m0 + wm * 64 + i * 16 + quad * 4 + rr;
        if (m >= M_ROWS) continue;
        int b = m / NTOK, n = m - b * NTOK;
        #pragma unroll
        for (int j = 0; j < 4; ++j) {
          int o = o0loc + wo * 64 + j * 16 + l16;
          int h = o >> 6, dd = o & 63;
          _Float16 val = (_Float16)acc[i][j][rr];
          if (t == 0)
            q[((size_t)(b * NH + h) * NTOK + n) * HD + dd] = val;
          else
            k[((size_t)(b * NH + h) * NTOK + n) * HD + dd] = val;
        }
      }
    }
  } else {
    // vT epilogue: per-wave LDS micro-transpose of each 16x16 fragment so
    // stores run along n (contiguous) instead of 2B-scatter at stride MPV.
    __syncthreads();                       // LDS reads of K-loop done
    _Float16* scrb = &As[0][0] + wave * 512;
    #pragma unroll
    for (int i = 0; i < 4; ++i) {
      #pragma unroll
      for (int j = 0; j < 4; ++j) {
        _Float16* scr = scrb + (j & 1) * 256;
        f16x4 wv;
        wv[0] = (_Float16)acc[i][j][0]; wv[1] = (_Float16)acc[i][j][1];
        wv[2] = (_Float16)acc[i][j][2]; wv[3] = (_Float16)acc[i][j][3];
        *(f16x4*)&scr[l16 * 16 + quad * 4] = wv;   // scr[dd][n_loc]
        asm volatile("s_waitcnt lgkmcnt(0)" ::: "memory");
        f16x4 rv = *(const f16x4*)&scr[(lane >> 2) * 16 + (lane & 3) * 4];
        int oc = o0loc + wo * 64 + j * 16 + (lane >> 2);
        int hh = oc >> 6, ddg = oc & 63;
        int mbase = m0 + wm * 64 + i * 16 + (lane & 3) * 4;
        int bb = mbase / NTOK, nn = mbase - bb * NTOK;
        _Float16* dst = &vT[((size_t)(bb * NH + hh) * HD + ddg) * MPV + nn];
        if (mbase + 3 < M_ROWS && nn + 3 < NTOK && !(nn & 1)) {
          f16x2 lo2, hi2;
          lo2[0] = rv[0]; lo2[1] = rv[1];
          hi2[0] = rv[2]; hi2[1] = rv[3];
          *(f16x2*)dst = lo2;
          *(f16x2*)(dst + 2) = hi2;
        } else {
          #pragma unroll
          for (int e = 0; e < 4; ++e) {
            int m = mbase + e;
            if (m < M_ROWS) {
              int b2 = m / NTOK, n2 = m - b2 * NTOK;
              vT[((size_t)(b2 * NH + hh) * HD + ddg) * MPV + n2] = rv[e];
            }
          }
        }
      }
    }
  }
}

// ---- zero the m-pad of vT (m in [577,640)).
__global__ void zerofill_vt(_Float16* __restrict__ vT) {
  int idx = blockIdx.x * 256 + threadIdx.x;
  int r = idx >> 6, c = idx & 63;
  if (r < 16 * NH * HD && c < MPV - NTOK)
    vT[(size_t)r * MPV + NTOK + c] = (_Float16)0.f;
}

// ---- Kernel 2: QK^T + Wpre mix + exp -> E (unnormalized) + partial rowsums.
__global__ __launch_bounds__(256) void qk_exp(
    const _Float16* __restrict__ q, const _Float16* __restrict__ k,
    const void* __restrict__ Wpre, const int* __restrict__ flagp,
    _Float16* __restrict__ E, float* __restrict__ Rp, int b0, int cb)
{
  const bool f32 = (*flagp != 0);
  __shared__ float wp[NH * NH];
  __shared__ _Float16 Es[NH * 16 * ESP];   // [g][n(16)][m(64)], pitch 72
  const int tid = threadIdx.x;
  if (tid < NH * NH) wp[tid] = ldin(Wpre, tid, f32) * 0.125f;  // fold scale
  __syncthreads();
  const int swz = xcd_swz(blockIdx.x, 370 * cb);
  const int bl = swz / 370;
  const int ny = (swz % 370) / 10;
  const int bx = swz % 10;
  const int lane = tid & 63, wave = tid >> 6;
  const int quad = lane >> 4, l16 = lane & 15;
  const int b = b0 + bl;
  const int n0 = ny * 16;
  const int m0 = bx * 64 + wave * 16;
  const int nq = min(n0 + l16, NTOK - 1);
  const int mk = min(m0 + l16, NTOK - 1);
  const size_t qbase = ((size_t)b * NH * NTOK + nq) * HD + quad * 8;
  const size_t kbase = ((size_t)b * NH * NTOK + mk) * HD + quad * 8;
  f32x4 acc[NH];
  #pragma unroll
  for (int h = 0; h < NH; ++h) {
    const size_t ho = (size_t)h * NTOK * HD;
    f16x8 a0 = *(const f16x8*)(q + qbase + ho);
    f16x8 bb0 = *(const f16x8*)(k + kbase + ho);
    f16x8 a1 = *(const f16x8*)(q + qbase + ho + 32);
    f16x8 bb1 = *(const f16x8*)(k + kbase + ho + 32);
    f32x4 z = {0.f, 0.f, 0.f, 0.f};
    z = MFMA16(a0, bb0, z);
    acc[h] = MFMA16(a1, bb1, z);
  }
  const int mloc = wave * 16 + l16;          // col within 64-wide tile
  const bool valid = (m0 + l16 < NTOK);
  #pragma unroll
  for (int g = 0; g < NH; ++g) {
    float s0 = 0.f, s1 = 0.f, s2 = 0.f, s3 = 0.f;
    #pragma unroll
    for (int h = 0; h < NH; ++h) {
      float w = wp[g * NH + h];
      s0 += w * acc[h][0]; s1 += w * acc[h][1];
      s2 += w * acc[h][2]; s3 += w * acc[h][3];
    }
    Es[(g * 16 + quad * 4 + 0) * ESP + mloc] = (_Float16)(valid ? __expf(s0) : 0.f);
    Es[(g * 16 + quad * 4 + 1) * ESP + mloc] = (_Float16)(valid ? __expf(s1) : 0.f);
    Es[(g * 16 + quad * 4 + 2) * ESP + mloc] = (_Float16)(valid ? __expf(s2) : 0.f);
    Es[(g * 16 + quad * 4 + 3) * ESP + mloc] = (_Float16)(valid ? __expf(s3) : 0.f);
  }
  __syncthreads();
  // cooperative full-line store: 8 lanes x 16 B = 128 B contiguous per row
  const int sub = tid & 7;
  const int rbk = tid >> 3;                  // 32 rows per pass
  #pragma unroll
  for (int it = 0; it < 6; ++it) {
    int idx = it * 32 + rbk;                 // 0..191
    int g = idx >> 4, n = idx & 15;
    f16x8 vv = *(const f16x8*)&Es[(g * 16 + n) * ESP + sub * 8];
    *(f16x8*)&E[((size_t)(bl * NH + g) * NPAD + n0 + n) * MPV + bx * 64 + sub * 8] = vv;
  }
  // partial rowsum of this block's 64 m-cols, per (g, n): Rp[b][g][bx][n]
  if (tid < NH * 16) {
    const _Float16* row = &Es[tid * ESP];
    float tot = 0.f;
    #pragma unroll
    for (int c = 0; c < 8; ++c) {
      f16x8 t = *(const f16x8*)&row[c * 8];
      #pragma unroll
      for (int j = 0; j < 8; ++j) tot += (float)t[j];
    }
    Rp[(((size_t)b * NH + (tid >> 4)) * 10 + bx) * NPAD + n0 + (tid & 15)] = tot;
  }
}

// ---- Kernel 3 phase-B body: normalize + Wpost mix (packed f16) -> P2s,
// PV via MFMA, double-buffered E prefetch across the lgkm-only barrier.
template<int NC, int D0>
__device__ __forceinline__ void pv_phaseB(
    const _Float16* __restrict__ E, const _Float16* __restrict__ vT,
    _Float16* P2s, const _Float16* w2s, const _Float16* rloc,
    f32x4 (&O)[3][4], int bl, int b, int n0, int w, int quad, int l16, int gg0)
{
  const int swz = (l16 & 7) << 3;
  const size_t ebase = ((size_t)(bl * NH) * NPAD + n0 + l16) * MPV
                     + w * 32 + quad * 8;
  const size_t estep = (size_t)NPAD * MPV;   // per-head stride
  f16x8 ev0[NH], ev1[NH];
  #pragma unroll
  for (int h = 0; h < NH; ++h)
    ev0[h] = *(const f16x8*)&E[ebase + h * estep + D0 * 128];
  #pragma unroll
  for (int i = 0; i < NC; ++i) {
    const int dmt = D0 + i;
    f16x8* cur = (i & 1) ? ev1 : ev0;
    f16x8* nxt = (i & 1) ? ev0 : ev1;
    BAR();                                    // previous P2s readers done
    if (i + 1 < NC) {                         // prefetch next chunk (in flight
      #pragma unroll                          // across both barriers below)
      for (int h = 0; h < NH; ++h)
        nxt[h] = *(const f16x8*)&E[ebase + h * estep + (dmt + 1) * 128];
    }
    #pragma unroll
    for (int h = 0; h < NH; ++h) cur[h] *= rloc[h];
    #pragma unroll
    for (int gp = 0; gp < NH; ++gp) {
      f16x8 p = cur[0] * w2s[gp * NH + 0];
      #pragma unroll
      for (int h = 1; h < NH; ++h) p += cur[h] * w2s[gp * NH + h];
      *(f16x8*)&P2s[gp * 2048 + l16 * 128 + ((w * 32 + quad * 8) ^ swz)] = p;
    }
    BAR();
    #pragma unroll
    for (int kc = 0; kc < 4; ++kc) {
      #pragma unroll
      for (int j = 0; j < 3; ++j) {
        const int g = gg0 + j;
        f16x8 a = *(const f16x8*)&P2s[g * 2048 + l16 * 128 + ((kc * 32 + quad * 8) ^ swz)];
        #pragma unroll
        for (int dt = 0; dt < 4; ++dt) {
          f16x8 bv = *(const f16x8*)(
              vT + ((size_t)(b * NH + g) * HD + dt * 16 + l16) * MPV
                 + dmt * 128 + kc * 32 + quad * 8);
          O[j][dt] = MFMA16(a, bv, O[j][dt]);
        }
      }
    }
  }
}

// ---- Kernel 3: rowsums from Rp partials, normalize + Wpost mix + PV.
__global__ __launch_bounds__(256) void pv_mix2(
    const _Float16* __restrict__ E, const _Float16* __restrict__ vT,
    const float* __restrict__ Rp, const void* __restrict__ Wpost,
    const int* __restrict__ flagp, float* __restrict__ Op0,
    float* __restrict__ Op1, int b0, int cb)
{
  const bool f32 = (*flagp != 0);
  __shared__ _Float16 P2s[NH * 16 * 128];   // XOR-swizzled, pitch 128
  __shared__ _Float16 w2s[NH * NH];
  __shared__ _Float16 rinvs[NH * 16];
  const int swz = xcd_swz(blockIdx.x, 74 * cb);
  const int bl = swz / 74;
  const int z = (swz % 74) / 37;
  const int nx = swz % 37;
  const int tid = threadIdx.x;
  const int lane = tid & 63, w = tid >> 6;
  const int quad = lane >> 4, l16 = lane & 15;
  const int n0 = nx * 16;
  const int b = b0 + bl;
  if (tid < NH * NH) w2s[tid] = (_Float16)ldin(Wpost, tid, f32);
  if (tid < NH * 16) {
    float tot = 0.f;
    #pragma unroll
    for (int mb = 0; mb < 10; ++mb)
      tot += Rp[(((size_t)b * NH + (tid >> 4)) * 10 + mb) * NPAD + n0 + (tid & 15)];
    rinvs[tid] = (_Float16)(tot > 0.f ? 1.f / tot : 0.f);
  }
  __syncthreads();
  _Float16 rloc[NH];
  #pragma unroll
  for (int h = 0; h < NH; ++h) rloc[h] = rinvs[h * 16 + l16];

  f32x4 O[3][4];
  #pragma unroll
  for (int j = 0; j < 3; ++j)
    #pragma unroll
    for (int dt = 0; dt < 4; ++dt) O[j][dt] = (f32x4){0.f, 0.f, 0.f, 0.f};
  const int gg0 = w * 3;

  if (z == 0)
    pv_phaseB<3, 0>(E, vT, P2s, w2s, rloc, O, bl, b, n0, w, quad, l16, gg0);
  else
    pv_phaseB<2, 3>(E, vT, P2s, w2s, rloc, O, bl, b, n0, w, quad, l16, gg0);

  float* __restrict__ Op = z ? Op1 : Op0;
  #pragma unroll
  for (int j = 0; j < 3; ++j)
    #pragma unroll
    for (int dt = 0; dt < 4; ++dt)
      #pragma unroll
      for (int r = 0; r < 4; ++r) {
        int n = n0 + quad * 4 + r;
        if (n < NTOK)
          Op[((size_t)bl * NTOK + n) * CH + (gg0 + j) * HD + dt * 16 + l16] =
              O[j][dt][r];
      }
}

// ---- Kernel 3b: o1 = (f16)(Op0 + Op1)
__global__ __launch_bounds__(256) void reduce_o1(
    const float* __restrict__ Op0, const float* __restrict__ Op1,
    _Float16* __restrict__ o1, int nelem)
{
  int i = (blockIdx.x * 256 + threadIdx.x) * 8;
  if (i >= nelem) return;
  float4 a0 = *(const float4*)(Op0 + i);
  float4 a1 = *(const float4*)(Op0 + i + 4);
  float4 c0 = *(const float4*)(Op1 + i);
  float4 c1 = *(const float4*)(Op1 + i + 4);
  f16x8 r;
  r[0] = (_Float16)(a0.x + c0.x); r[1] = (_Float16)(a0.y + c0.y);
  r[2] = (_Float16)(a0.z + c0.z); r[3] = (_Float16)(a0.w + c0.w);
  r[4] = (_Float16)(a1.x + c1.x); r[5] = (_Float16)(a1.y + c1.y);
  r[6] = (_Float16)(a1.z + c1.z); r[7] = (_Float16)(a1.w + c1.w);
  *(f16x8*)(o1 + i) = r;
}

// ---- Kernel 4: out = o1 @ Wproj^T + bproj, same m97-style staging.
__global__ __launch_bounds__(256) void gemm_proj_mfma(
    const _Float16* __restrict__ A, const _Float16* __restrict__ W,
    const void* __restrict__ bias, const int* __restrict__ flagp,
    void* __restrict__ out)
{
  const bool f32 = (*flagp != 0);
  __shared__ __align__(16) _Float16 As[2][128 * 32];
  __shared__ __align__(16) _Float16 Bs[2][128 * 32];
  const int swz = xcd_swz(blockIdx.x, 6 * 73);
  const int o0 = (swz % 6) * 128;
  const int m0 = (swz / 6) * 128;
  const int tid = threadIdx.x;
  const int lane = tid & 63, wave = tid >> 6;
  const int quad = lane >> 4, l16 = lane & 15;
  const int wm = wave & 1, wo = wave >> 1;

  const int row0 = wave * 32 + (lane >> 2);
  const int ch8  = (((lane & 3) ^ ((lane >> 3) & 3)) << 3);
  const int ar0 = min(m0 + row0, M_ROWS - 1);
  const int ar1 = min(m0 + row0 + 16, M_ROWS - 1);
  const int br0 = o0 + row0;
  const int br1 = o0 + row0 + 16;
  const int dl0 = wave * 1024 + lane * 8;
  const int dl1 = dl0 + 512;

  GLD16(A + (size_t)ar0 * CH + ch8, &As[0][dl0]);
  GLD16(A + (size_t)ar1 * CH + ch8, &As[0][dl1]);
  GLD16(W + (size_t)br0 * CH + ch8, &Bs[0][dl0]);
  GLD16(W + (size_t)br1 * CH + ch8, &Bs[0][dl1]);

  const int rdc = ((quad ^ ((l16 >> 1) & 3)) << 3);
  const int rdA = (wm * 64 + l16) * 32 + rdc;
  const int rdB = (wo * 64 + l16) * 32 + rdc;

  f32x4 acc[4][4] = {};
  int cur = 0;
  for (int ks = 0; ks < CH / 32; ++ks) {
    __syncthreads();
    if (ks + 1 < CH / 32) {
      const int kc = (ks + 1) * 32 + ch8;
      const int nb = cur ^ 1;
      GLD16(A + (size_t)ar0 * CH + kc, &As[nb][dl0]);
      GLD16(A + (size_t)ar1 * CH + kc, &As[nb][dl1]);
      GLD16(W + (size_t)br0 * CH + kc, &Bs[nb][dl0]);
      GLD16(W + (size_t)br1 * CH + kc, &Bs[nb][dl1]);
    }
    f16x8 af[4], bf_[4];
    #pragma unroll
    for (int i = 0; i < 4; ++i)
      af[i] = *(const f16x8*)&As[cur][rdA + i * 512];
    #pragma unroll
    for (int j = 0; j < 4; ++j)
      bf_[j] = *(const f16x8*)&Bs[cur][rdB + j * 512];
    #pragma unroll
    for (int i = 0; i < 4; ++i)
      #pragma unroll
      for (int j = 0; j < 4; ++j)
        acc[i][j] = MFMA16(af[i], bf_[j], acc[i][j]);
    cur ^= 1;
  }

  #pragma unroll
  for (int i = 0; i < 4; ++i) {
    #pragma unroll
    for (int rr = 0; rr < 4; ++rr) {
      int m = m0 + wm * 64 + i * 16 + quad * 4 + rr;
      if (m >= M_ROWS) continue;
      #pragma unroll
      for (int j = 0; j < 4; ++j) {
        int o = o0 + wo * 64 + j * 16 + l16;
        float val = acc[i][j][rr] + ldin(bias, o, f32);
        if (f32) ((float*)out)[(size_t)m * CH + o] = val;
        else ((__hip_bfloat16*)out)[(size_t)m * CH + o] = __float2bfloat16(val);
      }
    }
  }
}

extern "C" void kernel_launch(void* const* d_in, const int* in_sizes, int n_in,
                              void* d_out, int out_size, void* d_ws, size_t ws_size,
                              hipStream_t stream) {
  const void* x     = d_in[0];
  const void* Wqkv  = d_in[1];
  const void* Wproj = d_in[2];
  const void* bproj = d_in[3];
  const void* Wpre  = d_in[4];
  const void* Wpost = d_in[5];

  int* flag = (int*)d_ws;
  _Float16* ws = (_Float16*)((char*)d_ws + 16);
  const size_t QE  = (size_t)16 * NH * NTOK * HD;   // 7,090,176
  const size_t VTE = (size_t)16 * NH * HD * MPV;    // 7,864,320
  const size_t RPE = (size_t)16 * NH * 10 * NPAD;   // 1,136,640 f32
  const size_t EPB = (size_t)NH * NPAD * MPV;       // 4,546,560 f16 per batch
  const size_t OPB = (size_t)NTOK * CH;             //   443,136 f32 per batch

  _Float16* Xh  = ws;
  _Float16* Wqh = Xh + XHE;
  _Float16* Wph = Wqh + WQH;
  _Float16* q   = Wph + WPH;
  _Float16* k   = q + QE;
  _Float16* vT  = k + QE;
  _Float16* o1  = vT + VTE;
  float*    Rp  = (float*)(o1 + QE);

  // choose batch chunk from available workspace
  const size_t fixedB = 16 + ((size_t)XHE + WQH + WPH + 3 * QE + VTE) * sizeof(_Float16)
                      + RPE * sizeof(float);
  const size_t perB   = EPB * sizeof(_Float16) + 2 * OPB * sizeof(float);
  int cb = 16;
  while (cb > 1 && fixedB + (size_t)cb * perB > ws_size) cb >>= 1;

  _Float16* E   = (_Float16*)(Rp + RPE);
  float*    Op0 = (float*)(E + (size_t)cb * EPB);
  float*    Op1 = Op0 + (size_t)cb * OPB;

  dim3 blk(256);
  hipLaunchKernelGGL(detect_dtype, dim3(1), blk, 0, stream,
                     (const unsigned short*)x, flag);
  hipLaunchKernelGGL(cvt_all, dim3((XHE + WQH + WPH) / 8 / 256 + 1), blk, 0,
                     stream, x, Wqkv, Wproj, Xh, flag);
  hipLaunchKernelGGL(gemm_qkv_mfma, dim3(18 * 73), blk, 0, stream,
                     Xh, Wqh, q, k, vT);
  hipLaunchKernelGGL(zerofill_vt, dim3(16 * NH * HD * 64 / 256), blk, 0, stream, vT);
  for (int b0 = 0; b0 < 16; b0 += cb) {
    hipLaunchKernelGGL(qk_exp, dim3(370 * cb), blk, 0, stream,
                       q, k, Wpre, flag, E, Rp, b0, cb);
    hipLaunchKernelGGL(pv_mix2, dim3(74 * cb), blk, 0, stream,
                       E, vT, Rp, Wpost, flag, Op0, Op1, b0, cb);
    int nelem = cb * (int)OPB;
    hipLaunchKernelGGL(reduce_o1, dim3((nelem / 8 + 255) / 256), blk, 0, stream,
                       Op0, Op1, o1 + (size_t)b0 * OPB, nelem);
  }
  hipLaunchKernelGGL(gemm_proj_mfma, dim3(6 * 73), blk, 0, stream,
                     o1, Wph, bproj, flag, d_out);
}